// Round 4
// baseline (238.106 us; speedup 1.0000x reference)
//
#include <hip/hip_runtime.h>

#define SEQ 2048
#define BATCH 2
#define DM 1024
#define NH 16
#define DK 64
#define BH (BATCH*NH)

typedef __attribute__((ext_vector_type(8))) short bf16x8;
typedef __attribute__((ext_vector_type(4))) float f32x4;

__device__ __forceinline__ ushort f2bf(float f) {
  union { float f; unsigned u; } v; v.f = f;
  unsigned r = (v.u + 0x7fffu + ((v.u >> 16) & 1u)) >> 16;
  return (ushort)r;
}
__device__ __forceinline__ float bf2f(ushort h) {
  union { unsigned u; float f; } v; v.u = ((unsigned)h) << 16;
  return v.f;
}
// pack two f32 -> two bf16 in one u32 (RNE), gfx950 has no builtin (m240)
__device__ __forceinline__ unsigned cvtpk(float lo, float hi) {
  unsigned r;
  asm("v_cvt_pk_bf16_f32 %0, %1, %2" : "=v"(r) : "v"(lo), "v"(hi));
  return r;
}

// ---------------- batched cast fp32 -> bf16 (z = tensor index) ----------------
struct P4 { const float* p0; const float* p1; const float* p2; const float* p3; };
__global__ void k_castN(P4 in, ushort* __restrict__ out, int n4) {
  const float* src = (blockIdx.z == 0) ? in.p0 : (blockIdx.z == 1) ? in.p1
                    : (blockIdx.z == 2) ? in.p2 : in.p3;
  ushort* dst = out + (size_t)blockIdx.z * (size_t)n4 * 4;
  int i = blockIdx.x * blockDim.x + threadIdx.x;
  int st = gridDim.x * blockDim.x;
  for (; i < n4; i += st) {
    float4 v = reinterpret_cast<const float4*>(src)[i];
    ushort4 o;
    o.x = f2bf(v.x); o.y = f2bf(v.y); o.z = f2bf(v.z); o.w = f2bf(v.w);
    reinterpret_cast<ushort4*>(dst)[i] = o;
  }
}

// ---------------- RoPE cos/sin table: [SEQ][32] pairs ----------------
__global__ void k_rope_tab(float* __restrict__ tab) {
  int id = blockIdx.x * blockDim.x + threadIdx.x;
  if (id >= SEQ * 32) return;
  int s = id >> 5, i = id & 31;
  float inv = powf(10000.f, -(float)i / 32.f);
  float ang = (float)s * inv;
  float sn, cs;
  sincosf(ang, &sn, &cs);
  tab[id * 2] = cs;
  tab[id * 2 + 1] = sn;
}

// ---------------- RoPE apply + head-transpose: Y[b,s,h*64+d] -> T[bh,s,d] ----------------
// scale folds softmax 1/sqrt(dk) * log2(e) into Q (fp32, pre-quantization)
__global__ void k_rope(const ushort* __restrict__ Y, ushort* __restrict__ T,
                       const float* __restrict__ tab, float scale) {
  int idx = blockIdx.x * blockDim.x + threadIdx.x;
  if (idx >= BH * SEQ * 32) return;
  int i = idx & 31;
  int s = (idx >> 5) & (SEQ - 1);
  int bh = idx >> 16;            // SEQ*32 == 1<<16
  int b = bh >> 4, h = bh & 15;
  ushort2 x = *(const ushort2*)(Y + (size_t)(b * SEQ + s) * DM + h * 64 + 2 * i);
  float xe = bf2f(x.x), xo = bf2f(x.y);
  float cs = tab[((s << 5) + i) * 2], sn = tab[((s << 5) + i) * 2 + 1];
  ushort2 o;
  o.x = f2bf((xe * cs - xo * sn) * scale);
  o.y = f2bf((xe * sn + xo * cs) * scale);
  *(ushort2*)(T + (size_t)(bh * SEQ + s) * 64 + 2 * i) = o;
}

// ---------------- V transpose: Y[b,s,h*64+d] -> VT[bh, d, s] ----------------
__global__ __launch_bounds__(256) void k_tr_v(const ushort* __restrict__ Y,
                                              ushort* __restrict__ VT) {
  __shared__ ushort tile[64][65];
  const int st = blockIdx.x, bh = blockIdx.y;
  const int b = bh >> 4, h = bh & 15;
  const int d = threadIdx.x & 63, s4 = threadIdx.x >> 6;
#pragma unroll
  for (int p = 0; p < 16; ++p) {
    int sl = p * 4 + s4;
    tile[d][sl] = Y[(size_t)(b * SEQ + st * 64 + sl) * DM + h * 64 + d];
  }
  __syncthreads();
  const int sl = threadIdx.x & 63, d4 = threadIdx.x >> 6;
#pragma unroll
  for (int p = 0; p < 16; ++p) {
    int dl = p * 4 + d4;
    VT[(size_t)bh * DK * SEQ + (size_t)dl * SEQ + st * 64 + sl] = tile[dl][sl];
  }
}

// ---------------- async global->LDS 16B ----------------
__device__ __forceinline__ void gll16(const void* g, void* l) {
  __builtin_amdgcn_global_load_lds((const __attribute__((address_space(1))) void*)g,
                                   (__attribute__((address_space(3))) void*)l, 16, 0, 0);
}

// ---------------- GEMM: C[M,N] = A[M,K] * Bw[N,K]^T  (bf16 in, OUT out) ----------------
// blockIdx.z batches independent (A, Bw, C) triples (contiguous in memory).
template <typename OUT>
__global__ __launch_bounds__(256) void k_gemm_bt(const ushort* __restrict__ A,
                                                 const ushort* __restrict__ Bw,
                                                 OUT* __restrict__ C, int M, int N, int K) {
  A += (size_t)blockIdx.z * ((size_t)M * K);
  Bw += (size_t)blockIdx.z * ((size_t)N * K);
  C += (size_t)blockIdx.z * ((size_t)M * N);
  __shared__ ushort As[128 * 32];
  __shared__ ushort Bs[128 * 32];
  const int tid = threadIdx.x;
  const int w = tid >> 6, lane = tid & 63;
  const int l15 = lane & 15, l4 = lane >> 4;
  const int m0 = blockIdx.y * 128, n0 = blockIdx.x * 128;
  const int wr = w >> 1, wc = w & 1;
  const int lrow = lane >> 2, lcol = (lane & 3) * 8;
  f32x4 acc[4][4] = {};
  for (int kk = 0; kk < K; kk += 32) {
    __syncthreads();
    gll16(A + (size_t)(m0 + w * 16 + lrow) * K + kk + lcol, (void*)(As + w * 512));
    gll16(A + (size_t)(m0 + 64 + w * 16 + lrow) * K + kk + lcol, (void*)(As + 2048 + w * 512));
    gll16(Bw + (size_t)(n0 + w * 16 + lrow) * K + kk + lcol, (void*)(Bs + w * 512));
    gll16(Bw + (size_t)(n0 + 64 + w * 16 + lrow) * K + kk + lcol, (void*)(Bs + 2048 + w * 512));
    __syncthreads();
    bf16x8 af[4], bfr[4];
#pragma unroll
    for (int i = 0; i < 4; ++i)
      af[i] = *(const bf16x8*)(As + (wr * 64 + i * 16 + l15) * 32 + l4 * 8);
#pragma unroll
    for (int i = 0; i < 4; ++i)
      bfr[i] = *(const bf16x8*)(Bs + (wc * 64 + i * 16 + l15) * 32 + l4 * 8);
#pragma unroll
    for (int mi = 0; mi < 4; ++mi)
#pragma unroll
      for (int ni = 0; ni < 4; ++ni)
        acc[mi][ni] = __builtin_amdgcn_mfma_f32_16x16x32_bf16(af[mi], bfr[ni], acc[mi][ni], 0, 0, 0);
  }
#pragma unroll
  for (int mi = 0; mi < 4; ++mi)
#pragma unroll
    for (int ni = 0; ni < 4; ++ni)
#pragma unroll
      for (int r = 0; r < 4; ++r) {
        int row = m0 + wr * 64 + mi * 16 + l4 * 4 + r;
        int col = n0 + wc * 64 + ni * 16 + l15;
        float v = acc[mi][ni][r];
        if constexpr (sizeof(OUT) == 2)
          C[(size_t)row * N + col] = (OUT)f2bf(v);
        else
          C[(size_t)row * N + col] = (OUT)v;
      }
}

// ---------------- causal flash attention (swapped-QK^T, K-pipelined, XCD-local) ----------------
// qT (pre-scaled by 0.125*log2e), kT: [bh, s, 64]   vT: [bh, 64, s]   AO: [b, s, h*64+d]
#define LOADK(KB, kt_) do {                                                    \
    const ushort* kb_ = kT + hb + (size_t)(kt_) * 64 * 64;                     \
    _Pragma("unroll")                                                          \
    for (int nf = 0; nf < 4; ++nf) {                                           \
      KB##0[nf] = *(const bf16x8*)(kb_ + (nf * 16 + l15) * 64 + l4 * 8);       \
      KB##1[nf] = *(const bf16x8*)(kb_ + (nf * 16 + l15) * 64 + 32 + l4 * 8);  \
    }                                                                          \
  } while (0)

#define STEP(KC, KN, kt_, DIAG, PREF) do {                                     \
    const ushort* vb_ = vT + vbase + (size_t)(kt_) * 64;                       \
    bf16x8 vf0[4], vf1[4];                                                     \
    _Pragma("unroll")                                                          \
    for (int df = 0; df < 4; ++df) {                                           \
      vf0[df] = *(const bf16x8*)(vb_ + (size_t)(df * 16 + l15) * SEQ + l4 * 8);\
      vf1[df] = *(const bf16x8*)(vb_ + (size_t)(df * 16 + l15) * SEQ + 32 + l4 * 8);\
    }                                                                          \
    float p[4][4];                                                             \
    _Pragma("unroll")                                                          \
    for (int nf = 0; nf < 4; ++nf) {                                           \
      f32x4 z = {0.f, 0.f, 0.f, 0.f};                                          \
      z = __builtin_amdgcn_mfma_f32_16x16x32_bf16(KC##0[nf], qb0, z, 0, 0, 0); \
      z = __builtin_amdgcn_mfma_f32_16x16x32_bf16(KC##1[nf], qb1, z, 0, 0, 0); \
      _Pragma("unroll")                                                        \
      for (int r = 0; r < 4; ++r) {                                            \
        float sc = z[r];                                                       \
        if (DIAG && (nf * 16 + l4 * 4 + r) > (w * 16 + l15)) sc = -INFINITY;   \
        p[nf][r] = sc;                                                         \
      }                                                                        \
    }                                                                          \
    if (PREF) { LOADK(KN, (kt_) + 1); }                                        \
    float m0_ = fmaxf(fmaxf(p[0][0], p[0][1]), fmaxf(p[0][2], p[0][3]));       \
    float m1_ = fmaxf(fmaxf(p[1][0], p[1][1]), fmaxf(p[1][2], p[1][3]));       \
    float m2_ = fmaxf(fmaxf(p[2][0], p[2][1]), fmaxf(p[2][2], p[2][3]));       \
    float m3_ = fmaxf(fmaxf(p[3][0], p[3][1]), fmaxf(p[3][2], p[3][3]));       \
    float mx = fmaxf(fmaxf(m0_, m1_), fmaxf(m2_, m3_));                        \
    mx = fmaxf(mx, __shfl_xor(mx, 16));                                        \
    mx = fmaxf(mx, __shfl_xor(mx, 32));                                        \
    const float mn = fmaxf(mrun, mx);                                          \
    const float so = __builtin_amdgcn_exp2f(mrun - mn);                        \
    float rs = 0.f;                                                            \
    _Pragma("unroll")                                                          \
    for (int nf = 0; nf < 4; ++nf) {                                           \
      float e0 = __builtin_amdgcn_exp2f(p[nf][0] - mn);                        \
      float e1 = __builtin_amdgcn_exp2f(p[nf][1] - mn);                        \
      float e2 = __builtin_amdgcn_exp2f(p[nf][2] - mn);                        \
      float e3 = __builtin_amdgcn_exp2f(p[nf][3] - mn);                        \
      p[nf][0] = e0; p[nf][1] = e1; p[nf][2] = e2; p[nf][3] = e3;              \
      rs += (e0 + e1) + (e2 + e3);                                             \
    }                                                                          \
    rs += __shfl_xor(rs, 16);                                                  \
    rs += __shfl_xor(rs, 32);                                                  \
    lrun = lrun * so + rs;                                                     \
    mrun = mn;                                                                 \
    float soq[4];                                                              \
    _Pragma("unroll")                                                          \
    for (int r = 0; r < 4; ++r) soq[r] = __shfl(so, l4 * 4 + r);               \
    _Pragma("unroll")                                                          \
    for (int df = 0; df < 4; ++df)                                             \
      _Pragma("unroll")                                                        \
      for (int r = 0; r < 4; ++r) acc[df][r] *= soq[r];                        \
    _Pragma("unroll")                                                          \
    for (int nf = 0; nf < 4; ++nf) {                                           \
      uint2 pk;                                                                \
      pk.x = cvtpk(p[nf][0], p[nf][1]);                                        \
      pk.y = cvtpk(p[nf][2], p[nf][3]);                                        \
      *(uint2*)(myP + ((l15 * 128 + nf * 32 + l4 * 8) ^ swz)) = pk;            \
    }                                                                          \
    const bf16x8 pa0 = *(const bf16x8*)(myP + ((l15 * 128 + l4 * 16) ^ swz));  \
    const bf16x8 pa1 = *(const bf16x8*)(myP + ((l15 * 128 + 64 + l4 * 16) ^ swz));\
    _Pragma("unroll")                                                          \
    for (int df = 0; df < 4; ++df) {                                           \
      acc[df] = __builtin_amdgcn_mfma_f32_16x16x32_bf16(pa0, vf0[df], acc[df], 0, 0, 0);\
      acc[df] = __builtin_amdgcn_mfma_f32_16x16x32_bf16(pa1, vf1[df], acc[df], 0, 0, 0);\
    }                                                                          \
  } while (0)

__global__ __launch_bounds__(256, 3) void k_flash(const ushort* __restrict__ qT,
                                                  const ushort* __restrict__ kT,
                                                  const ushort* __restrict__ vT,
                                                  ushort* __restrict__ AO) {
  __shared__ char Plds[4 * 2048];
  // XCD-locality swizzle: XCD = blockIdx.x % 8 (round-robin dispatch heuristic).
  // Each XCD gets heads {4x..4x+3} -> K+V working set 2MB, L2-resident.
  // qt descends with linear id -> longest blocks dispatch first per XCD.
  const int l = blockIdx.x;
  const int bh = (l & 7) * 4 + ((l >> 3) & 3);
  const int qt = (SEQ / 64 - 1) - (l >> 5);
  const int tid = threadIdx.x, w = tid >> 6, lane = tid & 63;
  const int l15 = lane & 15, l4 = lane >> 4;
  const size_t hb = (size_t)bh * SEQ * DK;
  const size_t vbase = (size_t)bh * DK * SEQ;
  const int qrow0 = qt * 64 + w * 16;
  const bf16x8 qb0 = *(const bf16x8*)(qT + hb + (size_t)(qrow0 + l15) * 64 + l4 * 8);
  const bf16x8 qb1 = *(const bf16x8*)(qT + hb + (size_t)(qrow0 + l15) * 64 + 32 + l4 * 8);
  f32x4 acc[4] = {};
  float mrun = -INFINITY, lrun = 0.f;
  char* myP = (char*)Plds + w * 2048;
  const int swz = (l15 & 7) << 4;
  bf16x8 kA0[4], kA1[4], kB0[4], kB1[4];
  LOADK(kA, 0);
  int kt = 0;
  for (; kt + 1 < qt; kt += 2) {
    STEP(kA, kB, kt, false, true);
    STEP(kB, kA, kt + 1, false, true);
  }
  if (kt < qt) {
    STEP(kA, kB, kt, false, true);
    STEP(kB, kA, qt, true, false);
  } else {
    STEP(kA, kB, qt, true, false);
  }
  const int b = bh >> 4, h = bh & 15;
  float lq[4];
#pragma unroll
  for (int r = 0; r < 4; ++r) lq[r] = __shfl(lrun, l4 * 4 + r);
#pragma unroll
  for (int r = 0; r < 4; ++r) {
    float inv = 1.f / lq[r];
    int qrow = qrow0 + l4 * 4 + r;
#pragma unroll
    for (int df = 0; df < 4; ++df) {
      AO[(size_t)(b * SEQ + qrow) * DM + h * 64 + df * 16 + l15] = f2bf(acc[df][r] * inv);
    }
  }
}

extern "C" void kernel_launch(void* const* d_in, const int* in_sizes, int n_in,
                              void* d_out, int out_size, void* d_ws, size_t ws_size,
                              hipStream_t stream) {
  const float* Q = (const float*)d_in[0];
  const float* K = (const float*)d_in[1];
  const float* V = (const float*)d_in[2];
  const float* wq = (const float*)d_in[3];
  const float* wk = (const float*)d_in[4];
  const float* wv = (const float*)d_in[5];
  const float* wo = (const float*)d_in[6];
  float* out = (float*)d_out;
  char* ws = (char*)d_ws;

  ushort* XQ = (ushort*)(ws + 0);          // 8 MB each (XQ,XK,XV contiguous)
  ushort* WQ = (ushort*)(ws + 25165824);   // 2 MB each (WQ,WK,WV,WO contiguous)
  ushort* YQ = (ushort*)(ws + 33554432);   // 8 MB each (YQ,YK,YV contiguous)
  ushort* YK = (ushort*)(ws + 41943040);
  ushort* YV = (ushort*)(ws + 50331648);
  float* TAB = (float*)(ws + 58720256);    // 512 KB
  // aliases (stream-ordered reuse)
  ushort* qTt = XQ;
  ushort* kTt = (ushort*)(ws + 8388608);
  ushort* vTt = (ushort*)(ws + 16777216);
  ushort* AO = YQ;

  const int NX4 = BATCH * SEQ * DM / 4;
  const int NW4 = DM * DM / 4;
  P4 xin = {Q, K, V, nullptr};
  P4 win = {wq, wk, wv, wo};
  k_castN<<<dim3(1024, 1, 3), 256, 0, stream>>>(xin, XQ, NX4);
  k_castN<<<dim3(1024, 1, 4), 256, 0, stream>>>(win, WQ, NW4);
  k_rope_tab<<<(SEQ * 32) / 256, 256, 0, stream>>>(TAB);

  // QKV projections in one dispatch (grid.z = 3 -> 768 blocks, 3 blocks/CU)
  k_gemm_bt<ushort><<<dim3(DM / 128, (BATCH * SEQ) / 128, 3), 256, 0, stream>>>(
      XQ, WQ, YQ, BATCH * SEQ, DM, DM);

  const float QSCALE = 0.125f * 1.4426950408889634f;  // 1/sqrt(dk) * log2(e)
  k_rope<<<(BH * SEQ * 32) / 256, 256, 0, stream>>>(YQ, qTt, TAB, QSCALE);
  k_rope<<<(BH * SEQ * 32) / 256, 256, 0, stream>>>(YK, kTt, TAB, 1.0f);
  k_tr_v<<<dim3(SEQ / 64, BH), 256, 0, stream>>>(YV, vTt);

  k_flash<<<BH * (SEQ / 64), 256, 0, stream>>>(qTt, kTt, vTt, AO);

  k_gemm_bt<float><<<dim3(DM / 128, (BATCH * SEQ) / 128, 1), 256, 0, stream>>>(
      AO, WQ + 3 * DM * DM, out, BATCH * SEQ, DM, DM);
}

// Round 5
// 148.745 us; speedup vs baseline: 1.6008x; 1.6008x over previous
//
#include <hip/hip_runtime.h>

#define SEQ 2048
#define BATCH 2
#define DM 1024
#define NH 16
#define DK 64
#define BH (BATCH*NH)

typedef __attribute__((ext_vector_type(8))) short bf16x8;
typedef __attribute__((ext_vector_type(4))) float f32x4;

__device__ __forceinline__ ushort f2bf(float f) {
  union { float f; unsigned u; } v; v.f = f;
  unsigned r = (v.u + 0x7fffu + ((v.u >> 16) & 1u)) >> 16;
  return (ushort)r;
}
__device__ __forceinline__ float bf2f(ushort h) {
  union { unsigned u; float f; } v; v.u = ((unsigned)h) << 16;
  return v.f;
}
// pack two f32 -> two bf16 in one u32 (RNE), gfx950 has no builtin (m240)
__device__ __forceinline__ unsigned cvtpk(float lo, float hi) {
  unsigned r;
  asm("v_cvt_pk_bf16_f32 %0, %1, %2" : "=v"(r) : "v"(lo), "v"(hi));
  return r;
}

// ---------------- batched cast fp32 -> bf16 (z = tensor index) ----------------
struct P4 { const float* p0; const float* p1; const float* p2; const float* p3; };
__global__ void k_castN(P4 in, ushort* __restrict__ out, int n4) {
  const float* src = (blockIdx.z == 0) ? in.p0 : (blockIdx.z == 1) ? in.p1
                    : (blockIdx.z == 2) ? in.p2 : in.p3;
  ushort* dst = out + (size_t)blockIdx.z * (size_t)n4 * 4;
  int i = blockIdx.x * blockDim.x + threadIdx.x;
  int st = gridDim.x * blockDim.x;
  for (; i < n4; i += st) {
    float4 v = reinterpret_cast<const float4*>(src)[i];
    ushort4 o;
    o.x = f2bf(v.x); o.y = f2bf(v.y); o.z = f2bf(v.z); o.w = f2bf(v.w);
    reinterpret_cast<ushort4*>(dst)[i] = o;
  }
}

// ---------------- RoPE cos/sin table: [SEQ][32] pairs ----------------
__global__ void k_rope_tab(float* __restrict__ tab) {
  int id = blockIdx.x * blockDim.x + threadIdx.x;
  if (id >= SEQ * 32) return;
  int s = id >> 5, i = id & 31;
  float inv = powf(10000.f, -(float)i / 32.f);
  float ang = (float)s * inv;
  float sn, cs;
  sincosf(ang, &sn, &cs);
  tab[id * 2] = cs;
  tab[id * 2 + 1] = sn;
}

// ---------------- RoPE apply + head-transpose: Y[b,s,h*64+d] -> T[bh,s,d] ----------------
// scale folds softmax 1/sqrt(dk) * log2(e) into Q (fp32, pre-quantization)
__global__ void k_rope(const ushort* __restrict__ Y, ushort* __restrict__ T,
                       const float* __restrict__ tab, float scale) {
  int idx = blockIdx.x * blockDim.x + threadIdx.x;
  if (idx >= BH * SEQ * 32) return;
  int i = idx & 31;
  int s = (idx >> 5) & (SEQ - 1);
  int bh = idx >> 16;            // SEQ*32 == 1<<16
  int b = bh >> 4, h = bh & 15;
  ushort2 x = *(const ushort2*)(Y + (size_t)(b * SEQ + s) * DM + h * 64 + 2 * i);
  float xe = bf2f(x.x), xo = bf2f(x.y);
  float cs = tab[((s << 5) + i) * 2], sn = tab[((s << 5) + i) * 2 + 1];
  ushort2 o;
  o.x = f2bf((xe * cs - xo * sn) * scale);
  o.y = f2bf((xe * sn + xo * cs) * scale);
  *(ushort2*)(T + (size_t)(bh * SEQ + s) * 64 + 2 * i) = o;
}

// ---------------- V transpose: Y[b,s,h*64+d] -> VT[bh, d, s] ----------------
__global__ __launch_bounds__(256) void k_tr_v(const ushort* __restrict__ Y,
                                              ushort* __restrict__ VT) {
  __shared__ ushort tile[64][65];
  const int st = blockIdx.x, bh = blockIdx.y;
  const int b = bh >> 4, h = bh & 15;
  const int d = threadIdx.x & 63, s4 = threadIdx.x >> 6;
#pragma unroll
  for (int p = 0; p < 16; ++p) {
    int sl = p * 4 + s4;
    tile[d][sl] = Y[(size_t)(b * SEQ + st * 64 + sl) * DM + h * 64 + d];
  }
  __syncthreads();
  const int sl = threadIdx.x & 63, d4 = threadIdx.x >> 6;
#pragma unroll
  for (int p = 0; p < 16; ++p) {
    int dl = p * 4 + d4;
    VT[(size_t)bh * DK * SEQ + (size_t)dl * SEQ + st * 64 + sl] = tile[dl][sl];
  }
}

// ---------------- async global->LDS 16B ----------------
__device__ __forceinline__ void gll16(const void* g, void* l) {
  __builtin_amdgcn_global_load_lds((const __attribute__((address_space(1))) void*)g,
                                   (__attribute__((address_space(3))) void*)l, 16, 0, 0);
}

// ---------------- GEMM: C[M,N] = A[M,K] * Bw[N,K]^T  (bf16 in, OUT out) ----------------
// blockIdx.z batches independent (A, Bw, C) triples (contiguous in memory).
template <typename OUT>
__global__ __launch_bounds__(256) void k_gemm_bt(const ushort* __restrict__ A,
                                                 const ushort* __restrict__ Bw,
                                                 OUT* __restrict__ C, int M, int N, int K) {
  A += (size_t)blockIdx.z * ((size_t)M * K);
  Bw += (size_t)blockIdx.z * ((size_t)N * K);
  C += (size_t)blockIdx.z * ((size_t)M * N);
  __shared__ ushort As[128 * 32];
  __shared__ ushort Bs[128 * 32];
  const int tid = threadIdx.x;
  const int w = tid >> 6, lane = tid & 63;
  const int l15 = lane & 15, l4 = lane >> 4;
  const int m0 = blockIdx.y * 128, n0 = blockIdx.x * 128;
  const int wr = w >> 1, wc = w & 1;
  const int lrow = lane >> 2, lcol = (lane & 3) * 8;
  f32x4 acc[4][4] = {};
  for (int kk = 0; kk < K; kk += 32) {
    __syncthreads();
    gll16(A + (size_t)(m0 + w * 16 + lrow) * K + kk + lcol, (void*)(As + w * 512));
    gll16(A + (size_t)(m0 + 64 + w * 16 + lrow) * K + kk + lcol, (void*)(As + 2048 + w * 512));
    gll16(Bw + (size_t)(n0 + w * 16 + lrow) * K + kk + lcol, (void*)(Bs + w * 512));
    gll16(Bw + (size_t)(n0 + 64 + w * 16 + lrow) * K + kk + lcol, (void*)(Bs + 2048 + w * 512));
    __syncthreads();
    bf16x8 af[4], bfr[4];
#pragma unroll
    for (int i = 0; i < 4; ++i)
      af[i] = *(const bf16x8*)(As + (wr * 64 + i * 16 + l15) * 32 + l4 * 8);
#pragma unroll
    for (int i = 0; i < 4; ++i)
      bfr[i] = *(const bf16x8*)(Bs + (wc * 64 + i * 16 + l15) * 32 + l4 * 8);
#pragma unroll
    for (int mi = 0; mi < 4; ++mi)
#pragma unroll
      for (int ni = 0; ni < 4; ++ni)
        acc[mi][ni] = __builtin_amdgcn_mfma_f32_16x16x32_bf16(af[mi], bfr[ni], acc[mi][ni], 0, 0, 0);
  }
#pragma unroll
  for (int mi = 0; mi < 4; ++mi)
#pragma unroll
    for (int ni = 0; ni < 4; ++ni)
#pragma unroll
      for (int r = 0; r < 4; ++r) {
        int row = m0 + wr * 64 + mi * 16 + l4 * 4 + r;
        int col = n0 + wc * 64 + ni * 16 + l15;
        float v = acc[mi][ni][r];
        if constexpr (sizeof(OUT) == 2)
          C[(size_t)row * N + col] = (OUT)f2bf(v);
        else
          C[(size_t)row * N + col] = (OUT)v;
      }
}

// ---------------- causal flash attention (LDS-staged K/V, double-buffered) ----------------
// qT (pre-scaled by 0.125*log2e), kT: [bh, s, 64]   vT: [bh, 64, s]   AO: [b, s, h*64+d]
// K/V tiles staged ONCE per block into LDS via coalesced global_load_lds
// (pre-swizzled source -> linear LDS dest -> XOR-swizzled ds_read, rule #21).
// Fragment read: row*128B + ((c ^ (row&7))*16B) -> 2 lanes/bank (free).

// stage one 64x64 bf16 tile; rows of `src` are `srcstride` elems apart.
// chunk tt = i*256 + tid; row = tt>>3; source col-chunk c = (tt&7) ^ (row&7).
#define STAGE1(DST, src, srcstride) do {                                       \
    _Pragma("unroll")                                                          \
    for (int i_ = 0; i_ < 2; ++i_) {                                           \
      int tt_ = i_ * 256 + tid;                                                \
      int row_ = tt_ >> 3, c_ = (tt_ & 7) ^ (row_ & 7);                        \
      gll16(src + (size_t)row_ * (srcstride) + c_ * 8,                         \
            (void*)((char*)(DST) + (i_ * 256 + w * 64) * 16));                 \
    }                                                                          \
  } while (0)

#define STAGE(KD, VD, kt_) do {                                                \
    const ushort* kb_ = kT + hb + (size_t)(kt_) * 4096;                        \
    const ushort* vb_ = vT + vbase + (size_t)(kt_) * 64;                       \
    STAGE1(KD, kb_, 64);                                                       \
    STAGE1(VD, vb_, SEQ);                                                      \
  } while (0)

// read bf16x8 fragment: logical (row, col-chunk cidx) of a staged tile
#define LDSFRAG(BASE, row_, cidx)                                              \
  (*(const bf16x8*)((const char*)(BASE) + (row_) * 128 + (((cidx) ^ (l15 & 7)) * 16)))

#define STEP(KD, VD, KN, VN, kt_, DIAG, PREF) do {                             \
    if (PREF) { STAGE(KN, VN, (kt_) + 1); }                                    \
    float p[4][4];                                                             \
    _Pragma("unroll")                                                          \
    for (int nf = 0; nf < 4; ++nf) {                                           \
      bf16x8 k0_ = LDSFRAG(KD, nf * 16 + l15, l4);                             \
      bf16x8 k1_ = LDSFRAG(KD, nf * 16 + l15, l4 + 4);                         \
      f32x4 z = {0.f, 0.f, 0.f, 0.f};                                          \
      z = __builtin_amdgcn_mfma_f32_16x16x32_bf16(k0_, qb0, z, 0, 0, 0);       \
      z = __builtin_amdgcn_mfma_f32_16x16x32_bf16(k1_, qb1, z, 0, 0, 0);       \
      _Pragma("unroll")                                                        \
      for (int r = 0; r < 4; ++r) {                                            \
        float sc = z[r];                                                       \
        if (DIAG && (nf * 16 + l4 * 4 + r) > (w * 16 + l15)) sc = -INFINITY;   \
        p[nf][r] = sc;                                                         \
      }                                                                        \
    }                                                                          \
    float m0_ = fmaxf(fmaxf(p[0][0], p[0][1]), fmaxf(p[0][2], p[0][3]));       \
    float m1_ = fmaxf(fmaxf(p[1][0], p[1][1]), fmaxf(p[1][2], p[1][3]));       \
    float m2_ = fmaxf(fmaxf(p[2][0], p[2][1]), fmaxf(p[2][2], p[2][3]));       \
    float m3_ = fmaxf(fmaxf(p[3][0], p[3][1]), fmaxf(p[3][2], p[3][3]));       \
    float mx = fmaxf(fmaxf(m0_, m1_), fmaxf(m2_, m3_));                        \
    mx = fmaxf(mx, __shfl_xor(mx, 16));                                        \
    mx = fmaxf(mx, __shfl_xor(mx, 32));                                        \
    const float mn = fmaxf(mrun, mx);                                          \
    const float so = __builtin_amdgcn_exp2f(mrun - mn);                        \
    float rs = 0.f;                                                            \
    _Pragma("unroll")                                                          \
    for (int nf = 0; nf < 4; ++nf) {                                           \
      float e0 = __builtin_amdgcn_exp2f(p[nf][0] - mn);                        \
      float e1 = __builtin_amdgcn_exp2f(p[nf][1] - mn);                        \
      float e2 = __builtin_amdgcn_exp2f(p[nf][2] - mn);                        \
      float e3 = __builtin_amdgcn_exp2f(p[nf][3] - mn);                        \
      p[nf][0] = e0; p[nf][1] = e1; p[nf][2] = e2; p[nf][3] = e3;              \
      rs += (e0 + e1) + (e2 + e3);                                             \
    }                                                                          \
    rs += __shfl_xor(rs, 16);                                                  \
    rs += __shfl_xor(rs, 32);                                                  \
    lrun = lrun * so + rs;                                                     \
    mrun = mn;                                                                 \
    float soq[4];                                                              \
    _Pragma("unroll")                                                          \
    for (int r = 0; r < 4; ++r) soq[r] = __shfl(so, l4 * 4 + r);               \
    _Pragma("unroll")                                                          \
    for (int df = 0; df < 4; ++df)                                             \
      _Pragma("unroll")                                                        \
      for (int r = 0; r < 4; ++r) acc[df][r] *= soq[r];                        \
    _Pragma("unroll")                                                          \
    for (int nf = 0; nf < 4; ++nf) {                                           \
      uint2 pk;                                                                \
      pk.x = cvtpk(p[nf][0], p[nf][1]);                                        \
      pk.y = cvtpk(p[nf][2], p[nf][3]);                                        \
      *(uint2*)(myP + ((l15 * 128 + nf * 32 + l4 * 8) ^ swz)) = pk;            \
    }                                                                          \
    const bf16x8 pa0 = *(const bf16x8*)(myP + ((l15 * 128 + l4 * 16) ^ swz));  \
    const bf16x8 pa1 = *(const bf16x8*)(myP + ((l15 * 128 + 64 + l4 * 16) ^ swz));\
    _Pragma("unroll")                                                          \
    for (int df = 0; df < 4; ++df) {                                           \
      bf16x8 v0_ = LDSFRAG(VD, df * 16 + l15, l4);                             \
      bf16x8 v1_ = LDSFRAG(VD, df * 16 + l15, l4 + 4);                         \
      acc[df] = __builtin_amdgcn_mfma_f32_16x16x32_bf16(pa0, v0_, acc[df], 0, 0, 0);\
      acc[df] = __builtin_amdgcn_mfma_f32_16x16x32_bf16(pa1, v1_, acc[df], 0, 0, 0);\
    }                                                                          \
    __syncthreads();                                                           \
  } while (0)

__global__ __launch_bounds__(256, 4) void k_flash(const ushort* __restrict__ qT,
                                                  const ushort* __restrict__ kT,
                                                  const ushort* __restrict__ vT,
                                                  ushort* __restrict__ AO) {
  __shared__ ushort Ks[2][64 * 64];
  __shared__ ushort Vs[2][64 * 64];
  __shared__ char Plds[4 * 2048];
  // XCD-locality: heads grouped 4/XCD; qt descends -> longest blocks first.
  const int l = blockIdx.x;
  const int bh = (l & 7) * 4 + ((l >> 3) & 3);
  const int qt = (SEQ / 64 - 1) - (l >> 5);
  const int tid = threadIdx.x, w = tid >> 6, lane = tid & 63;
  const int l15 = lane & 15, l4 = lane >> 4;
  const size_t hb = (size_t)bh * SEQ * DK;
  const size_t vbase = (size_t)bh * DK * SEQ;
  const int qrow0 = qt * 64 + w * 16;
  const bf16x8 qb0 = *(const bf16x8*)(qT + hb + (size_t)(qrow0 + l15) * 64 + l4 * 8);
  const bf16x8 qb1 = *(const bf16x8*)(qT + hb + (size_t)(qrow0 + l15) * 64 + 32 + l4 * 8);
  f32x4 acc[4] = {};
  float mrun = -INFINITY, lrun = 0.f;
  char* myP = (char*)Plds + w * 2048;
  const int swz = (l15 & 7) << 4;
  STAGE(Ks[0], Vs[0], 0);
  __syncthreads();           // compiler drains vmcnt before barrier
  int kt = 0;
  for (; kt + 1 < qt; kt += 2) {
    STEP(Ks[0], Vs[0], Ks[1], Vs[1], kt, false, true);
    STEP(Ks[1], Vs[1], Ks[0], Vs[0], kt + 1, false, true);
  }
  if (kt < qt) {
    STEP(Ks[0], Vs[0], Ks[1], Vs[1], kt, false, true);
    STEP(Ks[1], Vs[1], Ks[0], Vs[0], qt, true, false);
  } else {
    STEP(Ks[0], Vs[0], Ks[1], Vs[1], qt, true, false);
  }
  const int b = bh >> 4, h = bh & 15;
  float lq[4];
#pragma unroll
  for (int r = 0; r < 4; ++r) lq[r] = __shfl(lrun, l4 * 4 + r);
#pragma unroll
  for (int r = 0; r < 4; ++r) {
    float inv = 1.f / lq[r];
    int qrow = qrow0 + l4 * 4 + r;
#pragma unroll
    for (int df = 0; df < 4; ++df) {
      AO[(size_t)(b * SEQ + qrow) * DM + h * 64 + df * 16 + l15] = f2bf(acc[df][r] * inv);
    }
  }
}

extern "C" void kernel_launch(void* const* d_in, const int* in_sizes, int n_in,
                              void* d_out, int out_size, void* d_ws, size_t ws_size,
                              hipStream_t stream) {
  const float* Q = (const float*)d_in[0];
  const float* K = (const float*)d_in[1];
  const float* V = (const float*)d_in[2];
  const float* wq = (const float*)d_in[3];
  const float* wk = (const float*)d_in[4];
  const float* wv = (const float*)d_in[5];
  const float* wo = (const float*)d_in[6];
  float* out = (float*)d_out;
  char* ws = (char*)d_ws;

  ushort* XQ = (ushort*)(ws + 0);          // 8 MB each (XQ,XK,XV contiguous)
  ushort* WQ = (ushort*)(ws + 25165824);   // 2 MB each (WQ,WK,WV,WO contiguous)
  ushort* YQ = (ushort*)(ws + 33554432);   // 8 MB each (YQ,YK,YV contiguous)
  ushort* YK = (ushort*)(ws + 41943040);
  ushort* YV = (ushort*)(ws + 50331648);
  float* TAB = (float*)(ws + 58720256);    // 512 KB
  // aliases (stream-ordered reuse)
  ushort* qTt = XQ;
  ushort* kTt = (ushort*)(ws + 8388608);
  ushort* vTt = (ushort*)(ws + 16777216);
  ushort* AO = YQ;

  const int NX4 = BATCH * SEQ * DM / 4;
  const int NW4 = DM * DM / 4;
  P4 xin = {Q, K, V, nullptr};
  P4 win = {wq, wk, wv, wo};
  k_castN<<<dim3(1024, 1, 3), 256, 0, stream>>>(xin, XQ, NX4);
  k_castN<<<dim3(1024, 1, 4), 256, 0, stream>>>(win, WQ, NW4);
  k_rope_tab<<<(SEQ * 32) / 256, 256, 0, stream>>>(TAB);

  // QKV projections in one dispatch (grid.z = 3 -> 768 blocks, 3 blocks/CU)
  k_gemm_bt<ushort><<<dim3(DM / 128, (BATCH * SEQ) / 128, 3), 256, 0, stream>>>(
      XQ, WQ, YQ, BATCH * SEQ, DM, DM);

  const float QSCALE = 0.125f * 1.4426950408889634f;  // 1/sqrt(dk) * log2(e)
  k_rope<<<(BH * SEQ * 32) / 256, 256, 0, stream>>>(YQ, qTt, TAB, QSCALE);
  k_rope<<<(BH * SEQ * 32) / 256, 256, 0, stream>>>(YK, kTt, TAB, 1.0f);
  k_tr_v<<<dim3(SEQ / 64, BH), 256, 0, stream>>>(YV, vTt);

  k_flash<<<BH * (SEQ / 64), 256, 0, stream>>>(qTt, kTt, vTt, AO);

  k_gemm_bt<float><<<dim3(DM / 128, (BATCH * SEQ) / 128, 1), 256, 0, stream>>>(
      AO, WQ + 3 * DM * DM, out, BATCH * SEQ, DM, DM);
}

// Round 6
// 146.012 us; speedup vs baseline: 1.6307x; 1.0187x over previous
//
#include <hip/hip_runtime.h>

#define SEQ 2048
#define BATCH 2
#define DM 1024
#define NH 16
#define DK 64
#define BH (BATCH*NH)

typedef __attribute__((ext_vector_type(8))) short bf16x8;
typedef __attribute__((ext_vector_type(4))) float f32x4;

__device__ __forceinline__ ushort f2bf(float f) {
  union { float f; unsigned u; } v; v.f = f;
  unsigned r = (v.u + 0x7fffu + ((v.u >> 16) & 1u)) >> 16;
  return (ushort)r;
}
__device__ __forceinline__ float bf2f(ushort h) {
  union { unsigned u; float f; } v; v.u = ((unsigned)h) << 16;
  return v.f;
}
// pack two f32 -> two bf16 in one u32 (RNE), gfx950 has no builtin (m240)
__device__ __forceinline__ unsigned cvtpk(float lo, float hi) {
  unsigned r;
  asm("v_cvt_pk_bf16_f32 %0, %1, %2" : "=v"(r) : "v"(lo), "v"(hi));
  return r;
}

// ---------------- batched cast fp32 -> bf16 (z = tensor index) ----------------
struct P4 { const float* p0; const float* p1; const float* p2; const float* p3; };
__global__ void k_castN(P4 in, ushort* __restrict__ out, int n4) {
  const float* src = (blockIdx.z == 0) ? in.p0 : (blockIdx.z == 1) ? in.p1
                    : (blockIdx.z == 2) ? in.p2 : in.p3;
  ushort* dst = out + (size_t)blockIdx.z * (size_t)n4 * 4;
  int i = blockIdx.x * blockDim.x + threadIdx.x;
  int st = gridDim.x * blockDim.x;
  for (; i < n4; i += st) {
    float4 v = reinterpret_cast<const float4*>(src)[i];
    ushort4 o;
    o.x = f2bf(v.x); o.y = f2bf(v.y); o.z = f2bf(v.z); o.w = f2bf(v.w);
    reinterpret_cast<ushort4*>(dst)[i] = o;
  }
}

// ---------------- RoPE cos/sin table: [SEQ][32] pairs ----------------
__global__ void k_rope_tab(float* __restrict__ tab) {
  int id = blockIdx.x * blockDim.x + threadIdx.x;
  if (id >= SEQ * 32) return;
  int s = id >> 5, i = id & 31;
  float inv = powf(10000.f, -(float)i / 32.f);
  float ang = (float)s * inv;
  float sn, cs;
  sincosf(ang, &sn, &cs);
  tab[id * 2] = cs;
  tab[id * 2 + 1] = sn;
}

// ---------------- V transpose: Y[b,s,h*64+d] -> VT[bh, d, s] ----------------
__global__ __launch_bounds__(256) void k_tr_v(const ushort* __restrict__ Y,
                                              ushort* __restrict__ VT) {
  __shared__ ushort tile[64][65];
  const int st = blockIdx.x, bh = blockIdx.y;
  const int b = bh >> 4, h = bh & 15;
  const int d = threadIdx.x & 63, s4 = threadIdx.x >> 6;
#pragma unroll
  for (int p = 0; p < 16; ++p) {
    int sl = p * 4 + s4;
    tile[d][sl] = Y[(size_t)(b * SEQ + st * 64 + sl) * DM + h * 64 + d];
  }
  __syncthreads();
  const int sl = threadIdx.x & 63, d4 = threadIdx.x >> 6;
#pragma unroll
  for (int p = 0; p < 16; ++p) {
    int dl = p * 4 + d4;
    VT[(size_t)bh * DK * SEQ + (size_t)dl * SEQ + st * 64 + sl] = tile[dl][sl];
  }
}

// ---------------- async global->LDS 16B ----------------
__device__ __forceinline__ void gll16(const void* g, void* l) {
  __builtin_amdgcn_global_load_lds((const __attribute__((address_space(1))) void*)g,
                                   (__attribute__((address_space(3))) void*)l, 16, 0, 0);
}

// ---------------- QKV GEMM with fused RoPE / head-transpose epilogue --------
// C = A[M,K] * Bw[N,K]^T per z slice (z=0:Q, 1:K, 2:V).
// z=0: rope(qscale) -> qT[bh,s,d];  z=1: rope(1) -> kT[bh,s,d];
// z=2: plain bf16 -> YV[b,s,h*64+d] (consumed by k_tr_v).
__global__ __launch_bounds__(256) void k_gemm_qkv(const ushort* __restrict__ A,
                                                  const ushort* __restrict__ Bw,
                                                  ushort* __restrict__ qT,
                                                  ushort* __restrict__ kT,
                                                  ushort* __restrict__ YV,
                                                  const float* __restrict__ tab,
                                                  float qscale, int M, int N, int K) {
  const int z = blockIdx.z;
  A += (size_t)z * ((size_t)M * K);
  Bw += (size_t)z * ((size_t)N * K);
  __shared__ ushort As[128 * 32];
  __shared__ ushort Bs[128 * 32];
  const int tid = threadIdx.x;
  const int w = tid >> 6, lane = tid & 63;
  const int l15 = lane & 15, l4 = lane >> 4;
  const int m0 = blockIdx.y * 128, n0 = blockIdx.x * 128;
  const int wr = w >> 1, wc = w & 1;
  const int lrow = lane >> 2, lcol = (lane & 3) * 8;
  f32x4 acc[4][4] = {};
  for (int kk = 0; kk < K; kk += 32) {
    __syncthreads();
    gll16(A + (size_t)(m0 + w * 16 + lrow) * K + kk + lcol, (void*)(As + w * 512));
    gll16(A + (size_t)(m0 + 64 + w * 16 + lrow) * K + kk + lcol, (void*)(As + 2048 + w * 512));
    gll16(Bw + (size_t)(n0 + w * 16 + lrow) * K + kk + lcol, (void*)(Bs + w * 512));
    gll16(Bw + (size_t)(n0 + 64 + w * 16 + lrow) * K + kk + lcol, (void*)(Bs + 2048 + w * 512));
    __syncthreads();
    bf16x8 af[4], bfr[4];
#pragma unroll
    for (int i = 0; i < 4; ++i)
      af[i] = *(const bf16x8*)(As + (wr * 64 + i * 16 + l15) * 32 + l4 * 8);
#pragma unroll
    for (int i = 0; i < 4; ++i)
      bfr[i] = *(const bf16x8*)(Bs + (wc * 64 + i * 16 + l15) * 32 + l4 * 8);
#pragma unroll
    for (int mi = 0; mi < 4; ++mi)
#pragma unroll
      for (int ni = 0; ni < 4; ++ni)
        acc[mi][ni] = __builtin_amdgcn_mfma_f32_16x16x32_bf16(af[mi], bfr[ni], acc[mi][ni], 0, 0, 0);
  }
  if (z == 2) {
#pragma unroll
    for (int mi = 0; mi < 4; ++mi)
#pragma unroll
      for (int ni = 0; ni < 4; ++ni)
#pragma unroll
        for (int r = 0; r < 4; ++r) {
          int row = m0 + wr * 64 + mi * 16 + l4 * 4 + r;
          int col = n0 + wc * 64 + ni * 16 + l15;
          YV[(size_t)row * N + col] = f2bf(acc[mi][ni][r]);
        }
  } else {
    const float scale = (z == 0) ? qscale : 1.0f;
    ushort* T = (z == 0) ? qT : kT;
    const bool odd = (l15 & 1);
#pragma unroll
    for (int mi = 0; mi < 4; ++mi)
#pragma unroll
      for (int ni = 0; ni < 4; ++ni)
#pragma unroll
        for (int r = 0; r < 4; ++r) {
          int row = m0 + wr * 64 + mi * 16 + l4 * 4 + r;
          int col = n0 + wc * 64 + ni * 16 + l15;
          float v = acc[mi][ni][r];
          float pv = __shfl_xor(v, 1);
          int s = row & (SEQ - 1);
          int d = col & 63;
          float2 cs = *(const float2*)(tab + ((size_t)s * 32 + (d >> 1)) * 2);
          float xe = odd ? pv : v, xo = odd ? v : pv;
          float outv = (odd ? (xe * cs.y + xo * cs.x) : (xe * cs.x - xo * cs.y)) * scale;
          int bh = (row >> 11) * 16 + (col >> 6);
          T[((size_t)bh * SEQ + s) * 64 + d] = f2bf(outv);
        }
  }
}

// ---------------- final GEMM: out[M,N] = A[M,K] * Bw[N,K]^T, fp32 out --------
// BM=64 x BN=128 tile -> 512 blocks (2 blocks/CU) for latency hiding.
__global__ __launch_bounds__(256) void k_gemm_f(const ushort* __restrict__ A,
                                                const ushort* __restrict__ Bw,
                                                float* __restrict__ C, int M, int N, int K) {
  __shared__ ushort As[64 * 32];
  __shared__ ushort Bs[128 * 32];
  const int tid = threadIdx.x;
  const int w = tid >> 6, lane = tid & 63;
  const int l15 = lane & 15, l4 = lane >> 4;
  const int m0 = blockIdx.y * 64, n0 = blockIdx.x * 128;
  const int wr = w >> 1, wc = w & 1;
  const int srow = tid >> 2, scol = (tid & 3) * 8;
  f32x4 acc[2][4] = {};
  for (int kk = 0; kk < K; kk += 32) {
    __syncthreads();
    gll16(A + (size_t)(m0 + srow) * K + kk + scol, (void*)(As + w * 512));
    gll16(Bw + (size_t)(n0 + srow) * K + kk + scol, (void*)(Bs + w * 512));
    gll16(Bw + (size_t)(n0 + 64 + srow) * K + kk + scol, (void*)(Bs + 2048 + w * 512));
    __syncthreads();
    bf16x8 af[2], bfr[4];
#pragma unroll
    for (int i = 0; i < 2; ++i)
      af[i] = *(const bf16x8*)(As + (wr * 32 + i * 16 + l15) * 32 + l4 * 8);
#pragma unroll
    for (int i = 0; i < 4; ++i)
      bfr[i] = *(const bf16x8*)(Bs + (wc * 64 + i * 16 + l15) * 32 + l4 * 8);
#pragma unroll
    for (int mi = 0; mi < 2; ++mi)
#pragma unroll
      for (int ni = 0; ni < 4; ++ni)
        acc[mi][ni] = __builtin_amdgcn_mfma_f32_16x16x32_bf16(af[mi], bfr[ni], acc[mi][ni], 0, 0, 0);
  }
#pragma unroll
  for (int mi = 0; mi < 2; ++mi)
#pragma unroll
    for (int ni = 0; ni < 4; ++ni)
#pragma unroll
      for (int r = 0; r < 4; ++r) {
        int row = m0 + wr * 32 + mi * 16 + l4 * 4 + r;
        int col = n0 + wc * 64 + ni * 16 + l15;
        C[(size_t)row * N + col] = acc[mi][ni][r];
      }
}

// ---------------- causal flash attention (LDS-staged K/V, double-buffered) ----------------
// qT (pre-scaled by 0.125*log2e), kT: [bh, s, 64]   vT: [bh, 64, s]   AO: [b, s, h*64+d]
#define STAGE1(DST, src, srcstride) do {                                       \
    _Pragma("unroll")                                                          \
    for (int i_ = 0; i_ < 2; ++i_) {                                           \
      int tt_ = i_ * 256 + tid;                                                \
      int row_ = tt_ >> 3, c_ = (tt_ & 7) ^ (row_ & 7);                        \
      gll16(src + (size_t)row_ * (srcstride) + c_ * 8,                         \
            (void*)((char*)(DST) + (i_ * 256 + w * 64) * 16));                 \
    }                                                                          \
  } while (0)

#define STAGE(KD, VD, kt_) do {                                                \
    const ushort* kb_ = kT + hb + (size_t)(kt_) * 4096;                        \
    const ushort* vb_ = vT + vbase + (size_t)(kt_) * 64;                       \
    STAGE1(KD, kb_, 64);                                                       \
    STAGE1(VD, vb_, SEQ);                                                      \
  } while (0)

#define LDSFRAG(BASE, row_, cidx)                                              \
  (*(const bf16x8*)((const char*)(BASE) + (row_) * 128 + (((cidx) ^ (l15 & 7)) * 16)))

#define STEP(KD, VD, KN, VN, kt_, DIAG, PREF) do {                             \
    if (PREF) { STAGE(KN, VN, (kt_) + 1); }                                    \
    float p[4][4];                                                             \
    _Pragma("unroll")                                                          \
    for (int nf = 0; nf < 4; ++nf) {                                           \
      bf16x8 k0_ = LDSFRAG(KD, nf * 16 + l15, l4);                             \
      bf16x8 k1_ = LDSFRAG(KD, nf * 16 + l15, l4 + 4);                         \
      f32x4 z = {0.f, 0.f, 0.f, 0.f};                                          \
      z = __builtin_amdgcn_mfma_f32_16x16x32_bf16(k0_, qb0, z, 0, 0, 0);       \
      z = __builtin_amdgcn_mfma_f32_16x16x32_bf16(k1_, qb1, z, 0, 0, 0);       \
      _Pragma("unroll")                                                        \
      for (int r = 0; r < 4; ++r) {                                            \
        float sc = z[r];                                                       \
        if (DIAG && (nf * 16 + l4 * 4 + r) > (w * 16 + l15)) sc = -INFINITY;   \
        p[nf][r] = sc;                                                         \
      }                                                                        \
    }                                                                          \
    float m0_ = fmaxf(fmaxf(p[0][0], p[0][1]), fmaxf(p[0][2], p[0][3]));       \
    float m1_ = fmaxf(fmaxf(p[1][0], p[1][1]), fmaxf(p[1][2], p[1][3]));       \
    float m2_ = fmaxf(fmaxf(p[2][0], p[2][1]), fmaxf(p[2][2], p[2][3]));       \
    float m3_ = fmaxf(fmaxf(p[3][0], p[3][1]), fmaxf(p[3][2], p[3][3]));       \
    float mx = fmaxf(fmaxf(m0_, m1_), fmaxf(m2_, m3_));                        \
    mx = fmaxf(mx, __shfl_xor(mx, 16));                                        \
    mx = fmaxf(mx, __shfl_xor(mx, 32));                                        \
    const float mn = fmaxf(mrun, mx);                                          \
    const float so = __builtin_amdgcn_exp2f(mrun - mn);                        \
    float rs = 0.f;                                                            \
    _Pragma("unroll")                                                          \
    for (int nf = 0; nf < 4; ++nf) {                                           \
      float e0 = __builtin_amdgcn_exp2f(p[nf][0] - mn);                        \
      float e1 = __builtin_amdgcn_exp2f(p[nf][1] - mn);                        \
      float e2 = __builtin_amdgcn_exp2f(p[nf][2] - mn);                        \
      float e3 = __builtin_amdgcn_exp2f(p[nf][3] - mn);                        \
      p[nf][0] = e0; p[nf][1] = e1; p[nf][2] = e2; p[nf][3] = e3;              \
      rs += (e0 + e1) + (e2 + e3);                                             \
    }                                                                          \
    rs += __shfl_xor(rs, 16);                                                  \
    rs += __shfl_xor(rs, 32);                                                  \
    lrun = lrun * so + rs;                                                     \
    mrun = mn;                                                                 \
    float soq[4];                                                              \
    _Pragma("unroll")                                                          \
    for (int r = 0; r < 4; ++r) soq[r] = __shfl(so, l4 * 4 + r);               \
    _Pragma("unroll")                                                          \
    for (int df = 0; df < 4; ++df)                                             \
      _Pragma("unroll")                                                        \
      for (int r = 0; r < 4; ++r) acc[df][r] *= soq[r];                        \
    _Pragma("unroll")                                                          \
    for (int nf = 0; nf < 4; ++nf) {                                           \
      uint2 pk;                                                                \
      pk.x = cvtpk(p[nf][0], p[nf][1]);                                        \
      pk.y = cvtpk(p[nf][2], p[nf][3]);                                        \
      *(uint2*)(myP + ((l15 * 128 + nf * 32 + l4 * 8) ^ swz)) = pk;            \
    }                                                                          \
    const bf16x8 pa0 = *(const bf16x8*)(myP + ((l15 * 128 + l4 * 16) ^ swz));  \
    const bf16x8 pa1 = *(const bf16x8*)(myP + ((l15 * 128 + 64 + l4 * 16) ^ swz));\
    _Pragma("unroll")                                                          \
    for (int df = 0; df < 4; ++df) {                                           \
      bf16x8 v0_ = LDSFRAG(VD, df * 16 + l15, l4);                             \
      bf16x8 v1_ = LDSFRAG(VD, df * 16 + l15, l4 + 4);                         \
      acc[df] = __builtin_amdgcn_mfma_f32_16x16x32_bf16(pa0, v0_, acc[df], 0, 0, 0);\
      acc[df] = __builtin_amdgcn_mfma_f32_16x16x32_bf16(pa1, v1_, acc[df], 0, 0, 0);\
    }                                                                          \
    __syncthreads();                                                           \
  } while (0)

__global__ __launch_bounds__(256, 4) void k_flash(const ushort* __restrict__ qT,
                                                  const ushort* __restrict__ kT,
                                                  const ushort* __restrict__ vT,
                                                  ushort* __restrict__ AO) {
  __shared__ ushort Ks[2][64 * 64];
  __shared__ ushort Vs[2][64 * 64];
  __shared__ char Plds[4 * 2048];
  const int l = blockIdx.x;
  const int bh = (l & 7) * 4 + ((l >> 3) & 3);
  const int qt = (SEQ / 64 - 1) - (l >> 5);
  const int tid = threadIdx.x, w = tid >> 6, lane = tid & 63;
  const int l15 = lane & 15, l4 = lane >> 4;
  const size_t hb = (size_t)bh * SEQ * DK;
  const size_t vbase = (size_t)bh * DK * SEQ;
  const int qrow0 = qt * 64 + w * 16;
  const bf16x8 qb0 = *(const bf16x8*)(qT + hb + (size_t)(qrow0 + l15) * 64 + l4 * 8);
  const bf16x8 qb1 = *(const bf16x8*)(qT + hb + (size_t)(qrow0 + l15) * 64 + 32 + l4 * 8);
  f32x4 acc[4] = {};
  float mrun = -INFINITY, lrun = 0.f;
  char* myP = (char*)Plds + w * 2048;
  const int swz = (l15 & 7) << 4;
  STAGE(Ks[0], Vs[0], 0);
  __syncthreads();
  int kt = 0;
  for (; kt + 1 < qt; kt += 2) {
    STEP(Ks[0], Vs[0], Ks[1], Vs[1], kt, false, true);
    STEP(Ks[1], Vs[1], Ks[0], Vs[0], kt + 1, false, true);
  }
  if (kt < qt) {
    STEP(Ks[0], Vs[0], Ks[1], Vs[1], kt, false, true);
    STEP(Ks[1], Vs[1], Ks[0], Vs[0], qt, true, false);
  } else {
    STEP(Ks[0], Vs[0], Ks[1], Vs[1], qt, true, false);
  }
  const int b = bh >> 4, h = bh & 15;
  float lq[4];
#pragma unroll
  for (int r = 0; r < 4; ++r) lq[r] = __shfl(lrun, l4 * 4 + r);
#pragma unroll
  for (int r = 0; r < 4; ++r) {
    float inv = 1.f / lq[r];
    int qrow = qrow0 + l4 * 4 + r;
#pragma unroll
    for (int df = 0; df < 4; ++df) {
      AO[(size_t)(b * SEQ + qrow) * DM + h * 64 + df * 16 + l15] = f2bf(acc[df][r] * inv);
    }
  }
}

extern "C" void kernel_launch(void* const* d_in, const int* in_sizes, int n_in,
                              void* d_out, int out_size, void* d_ws, size_t ws_size,
                              hipStream_t stream) {
  const float* Q = (const float*)d_in[0];
  const float* K = (const float*)d_in[1];
  const float* V = (const float*)d_in[2];
  const float* wq = (const float*)d_in[3];
  const float* wk = (const float*)d_in[4];
  const float* wv = (const float*)d_in[5];
  const float* wo = (const float*)d_in[6];
  float* out = (float*)d_out;
  char* ws = (char*)d_ws;

  // layout (56.5 MB peak):
  ushort* XQ = (ushort*)(ws + 0);          // 8 MB each, XQ/XK/XV contiguous
  ushort* XK = (ushort*)(ws + 8388608);
  ushort* WQ = (ushort*)(ws + 25165824);   // 2 MB each, WQ..WO contiguous
  ushort* qT = (ushort*)(ws + 33554432);   // 8 MB
  ushort* kT = (ushort*)(ws + 41943040);   // 8 MB
  ushort* YV = (ushort*)(ws + 50331648);   // 8 MB
  float* TAB = (float*)(ws + 58720256);    // 512 KB
  // stream-ordered reuse:
  ushort* vT = XQ;   // tr_v output (XQ consumed by gemm_qkv)
  ushort* AO = XK;   // flash output (XK consumed by gemm_qkv)

  const int NX4 = BATCH * SEQ * DM / 4;
  const int NW4 = DM * DM / 4;
  P4 xin = {Q, K, V, nullptr};
  P4 win = {wq, wk, wv, wo};
  k_castN<<<dim3(1024, 1, 3), 256, 0, stream>>>(xin, XQ, NX4);
  k_castN<<<dim3(1024, 1, 4), 256, 0, stream>>>(win, WQ, NW4);
  k_rope_tab<<<(SEQ * 32) / 256, 256, 0, stream>>>(TAB);

  const float QSCALE = 0.125f * 1.4426950408889634f;  // 1/sqrt(dk) * log2(e)
  // QKV projections + fused RoPE/head-transpose epilogue (768 blocks)
  k_gemm_qkv<<<dim3(DM / 128, (BATCH * SEQ) / 128, 3), 256, 0, stream>>>(
      XQ, WQ, qT, kT, YV, TAB, QSCALE, BATCH * SEQ, DM, DM);

  k_tr_v<<<dim3(SEQ / 64, BH), 256, 0, stream>>>(YV, vT);

  k_flash<<<BH * (SEQ / 64), 256, 0, stream>>>(qT, kT, vT, AO);

  // final projection: 64x128 tiles -> 512 blocks (2 blocks/CU)
  k_gemm_f<<<dim3(DM / 128, (BATCH * SEQ) / 64), 256, 0, stream>>>(
      AO, WQ + 3 * DM * DM, out, BATCH * SEQ, DM, DM);
}

// Round 7
// 140.918 us; speedup vs baseline: 1.6897x; 1.0361x over previous
//
#include <hip/hip_runtime.h>

#define SEQ 2048
#define BATCH 2
#define DM 1024
#define NH 16
#define DK 64
#define BH (BATCH*NH)

typedef __attribute__((ext_vector_type(8))) short bf16x8;
typedef __attribute__((ext_vector_type(4))) float f32x4;

__device__ __forceinline__ ushort f2bf(float f) {
  union { float f; unsigned u; } v; v.f = f;
  unsigned r = (v.u + 0x7fffu + ((v.u >> 16) & 1u)) >> 16;
  return (ushort)r;
}
__device__ __forceinline__ float bf2f(ushort h) {
  union { unsigned u; float f; } v; v.u = ((unsigned)h) << 16;
  return v.f;
}
__device__ __forceinline__ unsigned cvtpk(float lo, float hi) {
  unsigned r;
  asm("v_cvt_pk_bf16_f32 %0, %1, %2" : "=v"(r) : "v"(lo), "v"(hi));
  return r;
}

// ---------------- batched cast fp32 -> bf16 (z = tensor index) ----------------
struct P4 { const float* p0; const float* p1; const float* p2; const float* p3; };
__global__ void k_castN(P4 in, ushort* __restrict__ out, int n4) {
  const float* src = (blockIdx.z == 0) ? in.p0 : (blockIdx.z == 1) ? in.p1
                    : (blockIdx.z == 2) ? in.p2 : in.p3;
  ushort* dst = out + (size_t)blockIdx.z * (size_t)n4 * 4;
  int i = blockIdx.x * blockDim.x + threadIdx.x;
  int st = gridDim.x * blockDim.x;
  for (; i < n4; i += st) {
    float4 v = reinterpret_cast<const float4*>(src)[i];
    ushort4 o;
    o.x = f2bf(v.x); o.y = f2bf(v.y); o.z = f2bf(v.z); o.w = f2bf(v.w);
    reinterpret_cast<ushort4*>(dst)[i] = o;
  }
}

// ---------------- RoPE cos/sin table: [SEQ][32] pairs ----------------
__global__ void k_rope_tab(float* __restrict__ tab) {
  int id = blockIdx.x * blockDim.x + threadIdx.x;
  if (id >= SEQ * 32) return;
  int s = id >> 5, i = id & 31;
  float inv = powf(10000.f, -(float)i / 32.f);
  float ang = (float)s * inv;
  float sn, cs;
  sincosf(ang, &sn, &cs);
  tab[id * 2] = cs;
  tab[id * 2 + 1] = sn;
}

// ---------------- V transpose: Y[b,s,h*64+d] -> VT[bh, d, s] ----------------
__global__ __launch_bounds__(256) void k_tr_v(const ushort* __restrict__ Y,
                                              ushort* __restrict__ VT) {
  __shared__ ushort tile[64][65];
  const int st = blockIdx.x, bh = blockIdx.y;
  const int b = bh >> 4, h = bh & 15;
  const int d = threadIdx.x & 63, s4 = threadIdx.x >> 6;
#pragma unroll
  for (int p = 0; p < 16; ++p) {
    int sl = p * 4 + s4;
    tile[d][sl] = Y[(size_t)(b * SEQ + st * 64 + sl) * DM + h * 64 + d];
  }
  __syncthreads();
  const int sl = threadIdx.x & 63, d4 = threadIdx.x >> 6;
#pragma unroll
  for (int p = 0; p < 16; ++p) {
    int dl = p * 4 + d4;
    VT[(size_t)bh * DK * SEQ + (size_t)dl * SEQ + st * 64 + sl] = tile[dl][sl];
  }
}

// ---------------- async global->LDS 16B ----------------
__device__ __forceinline__ void gll16(const void* g, void* l) {
  __builtin_amdgcn_global_load_lds((const __attribute__((address_space(1))) void*)g,
                                   (__attribute__((address_space(3))) void*)l, 16, 0, 0);
}

// ---------------- QKV GEMM (2-phase double-buffered) + fused RoPE epilogue ----
#define GSTAGE(AD, BD, kk_) do {                                               \
    gll16(A + (size_t)(m0 + w * 16 + lrow) * K + (kk_) + lcol, (void*)((AD) + w * 512));        \
    gll16(A + (size_t)(m0 + 64 + w * 16 + lrow) * K + (kk_) + lcol, (void*)((AD) + 2048 + w * 512)); \
    gll16(Bw + (size_t)(n0 + w * 16 + lrow) * K + (kk_) + lcol, (void*)((BD) + w * 512));       \
    gll16(Bw + (size_t)(n0 + 64 + w * 16 + lrow) * K + (kk_) + lcol, (void*)((BD) + 2048 + w * 512)); \
  } while (0)

#define GCOMP(AS_, BS_) do {                                                   \
    bf16x8 af[4], bfr[4];                                                      \
    _Pragma("unroll")                                                          \
    for (int i = 0; i < 4; ++i)                                                \
      af[i] = *(const bf16x8*)((AS_) + (wr * 64 + i * 16 + l15) * 32 + l4 * 8);\
    _Pragma("unroll")                                                          \
    for (int i = 0; i < 4; ++i)                                                \
      bfr[i] = *(const bf16x8*)((BS_) + (wc * 64 + i * 16 + l15) * 32 + l4 * 8);\
    _Pragma("unroll")                                                          \
    for (int mi = 0; mi < 4; ++mi)                                             \
      _Pragma("unroll")                                                        \
      for (int ni = 0; ni < 4; ++ni)                                           \
        acc[mi][ni] = __builtin_amdgcn_mfma_f32_16x16x32_bf16(af[mi], bfr[ni], acc[mi][ni], 0, 0, 0); \
  } while (0)

__global__ __launch_bounds__(256) void k_gemm_qkv(const ushort* __restrict__ A,
                                                  const ushort* __restrict__ Bw,
                                                  ushort* __restrict__ qT,
                                                  ushort* __restrict__ kT,
                                                  ushort* __restrict__ YV,
                                                  const float* __restrict__ tab,
                                                  float qscale, int M, int N, int K) {
  const int z = blockIdx.z;
  A += (size_t)z * ((size_t)M * K);
  Bw += (size_t)z * ((size_t)N * K);
  __shared__ ushort As0[128 * 32], Bs0[128 * 32];
  __shared__ ushort As1[128 * 32], Bs1[128 * 32];
  const int tid = threadIdx.x;
  const int w = tid >> 6, lane = tid & 63;
  const int l15 = lane & 15, l4 = lane >> 4;
  const int m0 = blockIdx.y * 128, n0 = blockIdx.x * 128;
  const int wr = w >> 1, wc = w & 1;
  const int lrow = lane >> 2, lcol = (lane & 3) * 8;
  f32x4 acc[4][4] = {};
  GSTAGE(As0, Bs0, 0);
  __syncthreads();
  for (int kk = 0; kk < K; kk += 64) {
    GSTAGE(As1, Bs1, kk + 32);
    GCOMP(As0, Bs0);
    __syncthreads();
    if (kk + 64 < K) GSTAGE(As0, Bs0, kk + 64);
    GCOMP(As1, Bs1);
    __syncthreads();
  }
  if (z == 2) {
#pragma unroll
    for (int mi = 0; mi < 4; ++mi)
#pragma unroll
      for (int ni = 0; ni < 4; ++ni)
#pragma unroll
        for (int r = 0; r < 4; ++r) {
          int row = m0 + wr * 64 + mi * 16 + l4 * 4 + r;
          int col = n0 + wc * 64 + ni * 16 + l15;
          YV[(size_t)row * N + col] = f2bf(acc[mi][ni][r]);
        }
  } else {
    const float scale = (z == 0) ? qscale : 1.0f;
    ushort* T = (z == 0) ? qT : kT;
    const bool odd = (l15 & 1);
#pragma unroll
    for (int mi = 0; mi < 4; ++mi)
#pragma unroll
      for (int ni = 0; ni < 4; ++ni)
#pragma unroll
        for (int r = 0; r < 4; ++r) {
          int row = m0 + wr * 64 + mi * 16 + l4 * 4 + r;
          int col = n0 + wc * 64 + ni * 16 + l15;
          float v = acc[mi][ni][r];
          float pv = __shfl_xor(v, 1);
          int s = row & (SEQ - 1);
          int d = col & 63;
          float2 cs = *(const float2*)(tab + ((size_t)s * 32 + (d >> 1)) * 2);
          float xe = odd ? pv : v, xo = odd ? v : pv;
          float outv = (odd ? (xe * cs.y + xo * cs.x) : (xe * cs.x - xo * cs.y)) * scale;
          int bh = (row >> 11) * 16 + (col >> 6);
          T[((size_t)bh * SEQ + s) * 64 + d] = f2bf(outv);
        }
  }
}

// ---------------- final GEMM (2-phase double-buffered), fp32 out -------------
#define FSTAGE(AD, BD, kk_) do {                                               \
    gll16(A + (size_t)(m0 + srow) * K + (kk_) + scol, (void*)((AD) + w * 512));\
    gll16(Bw + (size_t)(n0 + srow) * K + (kk_) + scol, (void*)((BD) + w * 512));\
    gll16(Bw + (size_t)(n0 + 64 + srow) * K + (kk_) + scol, (void*)((BD) + 2048 + w * 512)); \
  } while (0)

#define FCOMP(AS_, BS_) do {                                                   \
    bf16x8 af[2], bfr[4];                                                      \
    _Pragma("unroll")                                                          \
    for (int i = 0; i < 2; ++i)                                                \
      af[i] = *(const bf16x8*)((AS_) + (wr * 32 + i * 16 + l15) * 32 + l4 * 8);\
    _Pragma("unroll")                                                          \
    for (int i = 0; i < 4; ++i)                                                \
      bfr[i] = *(const bf16x8*)((BS_) + (wc * 64 + i * 16 + l15) * 32 + l4 * 8);\
    _Pragma("unroll")                                                          \
    for (int mi = 0; mi < 2; ++mi)                                             \
      _Pragma("unroll")                                                        \
      for (int ni = 0; ni < 4; ++ni)                                           \
        acc[mi][ni] = __builtin_amdgcn_mfma_f32_16x16x32_bf16(af[mi], bfr[ni], acc[mi][ni], 0, 0, 0); \
  } while (0)

__global__ __launch_bounds__(256) void k_gemm_f(const ushort* __restrict__ A,
                                                const ushort* __restrict__ Bw,
                                                float* __restrict__ C, int M, int N, int K) {
  __shared__ ushort As0[64 * 32], Bs0[128 * 32];
  __shared__ ushort As1[64 * 32], Bs1[128 * 32];
  const int tid = threadIdx.x;
  const int w = tid >> 6, lane = tid & 63;
  const int l15 = lane & 15, l4 = lane >> 4;
  const int m0 = blockIdx.y * 64, n0 = blockIdx.x * 128;
  const int wr = w >> 1, wc = w & 1;
  const int srow = tid >> 2, scol = (tid & 3) * 8;
  f32x4 acc[2][4] = {};
  FSTAGE(As0, Bs0, 0);
  __syncthreads();
  for (int kk = 0; kk < K; kk += 64) {
    FSTAGE(As1, Bs1, kk + 32);
    FCOMP(As0, Bs0);
    __syncthreads();
    if (kk + 64 < K) FSTAGE(As0, Bs0, kk + 64);
    FCOMP(As1, Bs1);
    __syncthreads();
  }
#pragma unroll
  for (int mi = 0; mi < 2; ++mi)
#pragma unroll
    for (int ni = 0; ni < 4; ++ni)
#pragma unroll
      for (int r = 0; r < 4; ++r) {
        int row = m0 + wr * 32 + mi * 16 + l4 * 4 + r;
        int col = n0 + wc * 64 + ni * 16 + l15;
        C[(size_t)row * N + col] = acc[mi][ni][r];
      }
}

// ---------------- causal flash attention: QBLK=128, 2 strips/wave ------------
// qT (pre-scaled by 0.125*log2e), kT: [bh, s, 64]   vT: [bh, 64, s]   AO: [b, s, h*64+d]
// Each wave owns 32 q-rows (2 strips of 16, 64 apart). K/V staged in LDS
// double-buffered; K-fragments read once per step, reused by both strips.
#define STAGE1(DST, src, srcstride) do {                                       \
    _Pragma("unroll")                                                          \
    for (int i_ = 0; i_ < 2; ++i_) {                                           \
      int tt_ = i_ * 256 + tid;                                                \
      int row_ = tt_ >> 3, c_ = (tt_ & 7) ^ (row_ & 7);                        \
      gll16(src + (size_t)row_ * (srcstride) + c_ * 8,                         \
            (void*)((char*)(DST) + (i_ * 256 + w * 64) * 16));                 \
    }                                                                          \
  } while (0)

#define STAGE(KD, VD, kt_) do {                                                \
    const ushort* kb_ = kT + hb + (size_t)(kt_) * 4096;                        \
    const ushort* vb_ = vT + vbase + (size_t)(kt_) * 64;                       \
    STAGE1(KD, kb_, 64);                                                       \
    STAGE1(VD, vb_, SEQ);                                                      \
  } while (0)

#define LDSFRAG(BASE, row_, cidx)                                              \
  (*(const bf16x8*)((const char*)(BASE) + (row_) * 128 + (((cidx) ^ (l15 & 7)) * 16)))

// softmax update for one strip: P in exp2 domain already scaled
#define SMAXUPD(P, MRUN, LRUN, SO) do {                                        \
    float a0 = fmaxf(fmaxf(P[0][0], P[0][1]), fmaxf(P[0][2], P[0][3]));        \
    float a1 = fmaxf(fmaxf(P[1][0], P[1][1]), fmaxf(P[1][2], P[1][3]));        \
    float a2 = fmaxf(fmaxf(P[2][0], P[2][1]), fmaxf(P[2][2], P[2][3]));        \
    float a3 = fmaxf(fmaxf(P[3][0], P[3][1]), fmaxf(P[3][2], P[3][3]));        \
    float mx = fmaxf(fmaxf(a0, a1), fmaxf(a2, a3));                            \
    mx = fmaxf(mx, __shfl_xor(mx, 16));                                        \
    mx = fmaxf(mx, __shfl_xor(mx, 32));                                        \
    const float mn = fmaxf(MRUN, mx);                                          \
    SO = __builtin_amdgcn_exp2f(MRUN - mn);                                    \
    float rs = 0.f;                                                            \
    _Pragma("unroll")                                                          \
    for (int nf = 0; nf < 4; ++nf) {                                           \
      float e0 = __builtin_amdgcn_exp2f(P[nf][0] - mn);                        \
      float e1 = __builtin_amdgcn_exp2f(P[nf][1] - mn);                        \
      float e2 = __builtin_amdgcn_exp2f(P[nf][2] - mn);                        \
      float e3 = __builtin_amdgcn_exp2f(P[nf][3] - mn);                        \
      P[nf][0] = e0; P[nf][1] = e1; P[nf][2] = e2; P[nf][3] = e3;              \
      rs += (e0 + e1) + (e2 + e3);                                             \
    }                                                                          \
    rs += __shfl_xor(rs, 16);                                                  \
    rs += __shfl_xor(rs, 32);                                                  \
    LRUN = LRUN * SO + rs;                                                     \
    MRUN = mn;                                                                 \
  } while (0)

#define RESCALE(ACC, SO) do {                                                  \
    float soq[4];                                                              \
    _Pragma("unroll")                                                          \
    for (int r = 0; r < 4; ++r) soq[r] = __shfl(SO, l4 * 4 + r);               \
    _Pragma("unroll")                                                          \
    for (int df = 0; df < 4; ++df)                                             \
      _Pragma("unroll")                                                        \
      for (int r = 0; r < 4; ++r) ACC[df][r] *= soq[r];                        \
  } while (0)

#define PWRITE(P, MYP) do {                                                    \
    _Pragma("unroll")                                                          \
    for (int nf = 0; nf < 4; ++nf) {                                           \
      uint2 pk;                                                                \
      pk.x = cvtpk(P[nf][0], P[nf][1]);                                        \
      pk.y = cvtpk(P[nf][2], P[nf][3]);                                        \
      *(uint2*)((MYP) + ((l15 * 128 + nf * 32 + l4 * 8) ^ swz)) = pk;          \
    }                                                                          \
  } while (0)

// M0/M1: -1 = skip strip, 0 = full, 1 = diagonal mask
#define STEP2(KC, VC, KN, VN, kt_, M0, M1, PREF) do {                          \
    if (PREF) { STAGE(KN, VN, (kt_) + 1); }                                    \
    float p0[4][4], p1[4][4];                                                  \
    _Pragma("unroll")                                                          \
    for (int nf = 0; nf < 4; ++nf) {                                           \
      bf16x8 k0_ = LDSFRAG(KC, nf * 16 + l15, l4);                             \
      bf16x8 k1_ = LDSFRAG(KC, nf * 16 + l15, l4 + 4);                         \
      if (M0 >= 0) {                                                           \
        f32x4 z = {0.f, 0.f, 0.f, 0.f};                                        \
        z = __builtin_amdgcn_mfma_f32_16x16x32_bf16(k0_, qb00, z, 0, 0, 0);    \
        z = __builtin_amdgcn_mfma_f32_16x16x32_bf16(k1_, qb01, z, 0, 0, 0);    \
        _Pragma("unroll")                                                      \
        for (int r = 0; r < 4; ++r) {                                          \
          float sc = z[r];                                                     \
          if (M0 == 1 && (nf * 16 + l4 * 4 + r) > (w * 16 + l15)) sc = -INFINITY; \
          p0[nf][r] = sc;                                                      \
        }                                                                      \
      }                                                                        \
      {                                                                        \
        f32x4 z = {0.f, 0.f, 0.f, 0.f};                                        \
        z = __builtin_amdgcn_mfma_f32_16x16x32_bf16(k0_, qb10, z, 0, 0, 0);    \
        z = __builtin_amdgcn_mfma_f32_16x16x32_bf16(k1_, qb11, z, 0, 0, 0);    \
        _Pragma("unroll")                                                      \
        for (int r = 0; r < 4; ++r) {                                          \
          float sc = z[r];                                                     \
          if (M1 == 1 && (nf * 16 + l4 * 4 + r) > (w * 16 + l15)) sc = -INFINITY; \
          p1[nf][r] = sc;                                                      \
        }                                                                      \
      }                                                                        \
    }                                                                          \
    float so0_, so1_;                                                          \
    if (M0 >= 0) { SMAXUPD(p0, mrun0, lrun0, so0_); RESCALE(acc0, so0_); PWRITE(p0, myP0); } \
    SMAXUPD(p1, mrun1, lrun1, so1_); RESCALE(acc1, so1_); PWRITE(p1, myP1);    \
    bf16x8 pa00, pa01, pa10, pa11;                                             \
    if (M0 >= 0) {                                                             \
      pa00 = *(const bf16x8*)(myP0 + ((l15 * 128 + l4 * 16) ^ swz));           \
      pa01 = *(const bf16x8*)(myP0 + ((l15 * 128 + 64 + l4 * 16) ^ swz));      \
    }                                                                          \
    pa10 = *(const bf16x8*)(myP1 + ((l15 * 128 + l4 * 16) ^ swz));             \
    pa11 = *(const bf16x8*)(myP1 + ((l15 * 128 + 64 + l4 * 16) ^ swz));        \
    _Pragma("unroll")                                                          \
    for (int df = 0; df < 4; ++df) {                                           \
      bf16x8 v0_ = LDSFRAG(VC, df * 16 + l15, l4);                             \
      bf16x8 v1_ = LDSFRAG(VC, df * 16 + l15, l4 + 4);                         \
      if (M0 >= 0) {                                                           \
        acc0[df] = __builtin_amdgcn_mfma_f32_16x16x32_bf16(pa00, v0_, acc0[df], 0, 0, 0); \
        acc0[df] = __builtin_amdgcn_mfma_f32_16x16x32_bf16(pa01, v1_, acc0[df], 0, 0, 0); \
      }                                                                        \
      acc1[df] = __builtin_amdgcn_mfma_f32_16x16x32_bf16(pa10, v0_, acc1[df], 0, 0, 0); \
      acc1[df] = __builtin_amdgcn_mfma_f32_16x16x32_bf16(pa11, v1_, acc1[df], 0, 0, 0); \
    }                                                                          \
    __syncthreads();                                                           \
  } while (0)

__global__ __launch_bounds__(256, 3) void k_flash(const ushort* __restrict__ qT,
                                                  const ushort* __restrict__ kT,
                                                  const ushort* __restrict__ vT,
                                                  ushort* __restrict__ AO) {
  __shared__ ushort Ks[2][64 * 64];
  __shared__ ushort Vs[2][64 * 64];
  __shared__ char Plds[4 * 4096];
  // grid 512 = 8 XCD slots x 4 heads x 16 q-tiles; longest (qt=15) first
  const int l = blockIdx.x;
  const int bh = (l & 7) * 4 + ((l >> 3) & 3);
  const int qt = (SEQ / 128 - 1) - (l >> 5);
  const int tid = threadIdx.x, w = tid >> 6, lane = tid & 63;
  const int l15 = lane & 15, l4 = lane >> 4;
  const size_t hb = (size_t)bh * SEQ * DK;
  const size_t vbase = (size_t)bh * DK * SEQ;
  const int qrow0 = qt * 128 + w * 16;       // strip0
  const int qrow1 = qrow0 + 64;              // strip1
  const bf16x8 qb00 = *(const bf16x8*)(qT + hb + (size_t)(qrow0 + l15) * 64 + l4 * 8);
  const bf16x8 qb01 = *(const bf16x8*)(qT + hb + (size_t)(qrow0 + l15) * 64 + 32 + l4 * 8);
  const bf16x8 qb10 = *(const bf16x8*)(qT + hb + (size_t)(qrow1 + l15) * 64 + l4 * 8);
  const bf16x8 qb11 = *(const bf16x8*)(qT + hb + (size_t)(qrow1 + l15) * 64 + 32 + l4 * 8);
  f32x4 acc0[4] = {}, acc1[4] = {};
  float mrun0 = -INFINITY, lrun0 = 0.f, mrun1 = -INFINITY, lrun1 = 0.f;
  char* myP0 = (char*)Plds + w * 4096;
  char* myP1 = myP0 + 2048;
  const int swz = (l15 & 7) << 4;
  ushort* kc = &Ks[0][0]; ushort* vc = &Vs[0][0];
  ushort* kn = &Ks[1][0]; ushort* vn = &Vs[1][0];
  STAGE(kc, vc, 0);
  __syncthreads();
  for (int kt = 0; kt < 2 * qt; ++kt) {
    STEP2(kc, vc, kn, vn, kt, 0, 0, true);
    ushort* t;
    t = kc; kc = kn; kn = t;
    t = vc; vc = vn; vn = t;
  }
  STEP2(kc, vc, kn, vn, 2 * qt, 1, 0, true);
  {
    ushort* t;
    t = kc; kc = kn; kn = t;
    t = vc; vc = vn; vn = t;
  }
  STEP2(kc, vc, kn, vn, 2 * qt + 1, -1, 1, false);
  const int b = bh >> 4, h = bh & 15;
  float lq0[4], lq1[4];
#pragma unroll
  for (int r = 0; r < 4; ++r) {
    lq0[r] = __shfl(lrun0, l4 * 4 + r);
    lq1[r] = __shfl(lrun1, l4 * 4 + r);
  }
#pragma unroll
  for (int r = 0; r < 4; ++r) {
    float inv0 = 1.f / lq0[r], inv1 = 1.f / lq1[r];
    int qr0 = qrow0 + l4 * 4 + r, qr1 = qrow1 + l4 * 4 + r;
#pragma unroll
    for (int df = 0; df < 4; ++df) {
      AO[(size_t)(b * SEQ + qr0) * DM + h * 64 + df * 16 + l15] = f2bf(acc0[df][r] * inv0);
      AO[(size_t)(b * SEQ + qr1) * DM + h * 64 + df * 16 + l15] = f2bf(acc1[df][r] * inv1);
    }
  }
}

extern "C" void kernel_launch(void* const* d_in, const int* in_sizes, int n_in,
                              void* d_out, int out_size, void* d_ws, size_t ws_size,
                              hipStream_t stream) {
  const float* Q = (const float*)d_in[0];
  const float* K = (const float*)d_in[1];
  const float* V = (const float*)d_in[2];
  const float* wq = (const float*)d_in[3];
  const float* wk = (const float*)d_in[4];
  const float* wv = (const float*)d_in[5];
  const float* wo = (const float*)d_in[6];
  float* out = (float*)d_out;
  char* ws = (char*)d_ws;

  ushort* XQ = (ushort*)(ws + 0);          // 8 MB each, XQ/XK/XV contiguous
  ushort* XK = (ushort*)(ws + 8388608);
  ushort* WQ = (ushort*)(ws + 25165824);   // 2 MB each, WQ..WO contiguous
  ushort* qT = (ushort*)(ws + 33554432);   // 8 MB
  ushort* kT = (ushort*)(ws + 41943040);   // 8 MB
  ushort* YV = (ushort*)(ws + 50331648);   // 8 MB
  float* TAB = (float*)(ws + 58720256);    // 512 KB
  // stream-ordered reuse:
  ushort* vT = XQ;   // tr_v output (XQ consumed by gemm_qkv)
  ushort* AO = XK;   // flash output (XK consumed by gemm_qkv)

  const int NX4 = BATCH * SEQ * DM / 4;
  const int NW4 = DM * DM / 4;
  P4 xin = {Q, K, V, nullptr};
  P4 win = {wq, wk, wv, wo};
  k_castN<<<dim3(1024, 1, 3), 256, 0, stream>>>(xin, XQ, NX4);
  k_castN<<<dim3(1024, 1, 4), 256, 0, stream>>>(win, WQ, NW4);
  k_rope_tab<<<(SEQ * 32) / 256, 256, 0, stream>>>(TAB);

  const float QSCALE = 0.125f * 1.4426950408889634f;  // 1/sqrt(dk) * log2(e)
  k_gemm_qkv<<<dim3(DM / 128, (BATCH * SEQ) / 128, 3), 256, 0, stream>>>(
      XQ, WQ, qT, kT, YV, TAB, QSCALE, BATCH * SEQ, DM, DM);

  k_tr_v<<<dim3(SEQ / 64, BH), 256, 0, stream>>>(YV, vT);

  k_flash<<<BH * (SEQ / 128), 256, 0, stream>>>(qT, kT, vT, AO);

  k_gemm_f<<<dim3(DM / 128, (BATCH * SEQ) / 64), 256, 0, stream>>>(
      AO, WQ + 3 * DM * DM, out, BATCH * SEQ, DM, DM);
}

// Round 8
// 130.238 us; speedup vs baseline: 1.8282x; 1.0820x over previous
//
#include <hip/hip_runtime.h>

#define SEQ 2048
#define BATCH 2
#define DM 1024
#define NH 16
#define DK 64
#define BH (BATCH*NH)

typedef __attribute__((ext_vector_type(8))) short bf16x8;
typedef __attribute__((ext_vector_type(4))) float f32x4;

__device__ __forceinline__ ushort f2bf(float f) {
  union { float f; unsigned u; } v; v.f = f;
  unsigned r = (v.u + 0x7fffu + ((v.u >> 16) & 1u)) >> 16;
  return (ushort)r;
}
__device__ __forceinline__ float bf2f(ushort h) {
  union { unsigned u; float f; } v; v.u = ((unsigned)h) << 16;
  return v.f;
}
__device__ __forceinline__ unsigned cvtpk(float lo, float hi) {
  unsigned r;
  asm("v_cvt_pk_bf16_f32 %0, %1, %2" : "=v"(r) : "v"(lo), "v"(hi));
  return r;
}

// counted-vmcnt sync primitives (T4): never drain vmcnt to 0 in the main loop
#define WAITV4 asm volatile("s_waitcnt vmcnt(4)" ::: "memory")
#define WAITV3 asm volatile("s_waitcnt vmcnt(3)" ::: "memory")
#define WAITV0 asm volatile("s_waitcnt vmcnt(0)" ::: "memory")
#define WAITL0 asm volatile("s_waitcnt lgkmcnt(0)" ::: "memory")
#define BARR() __builtin_amdgcn_s_barrier()

// ---------------- batched cast fp32 -> bf16 (z = tensor index) ----------------
struct P4 { const float* p0; const float* p1; const float* p2; const float* p3; };
__global__ void k_castN(P4 in, ushort* __restrict__ out, int n4) {
  const float* src = (blockIdx.z == 0) ? in.p0 : (blockIdx.z == 1) ? in.p1
                    : (blockIdx.z == 2) ? in.p2 : in.p3;
  ushort* dst = out + (size_t)blockIdx.z * (size_t)n4 * 4;
  int i = blockIdx.x * blockDim.x + threadIdx.x;
  int st = gridDim.x * blockDim.x;
  for (; i < n4; i += st) {
    float4 v = reinterpret_cast<const float4*>(src)[i];
    ushort4 o;
    o.x = f2bf(v.x); o.y = f2bf(v.y); o.z = f2bf(v.z); o.w = f2bf(v.w);
    reinterpret_cast<ushort4*>(dst)[i] = o;
  }
}

// ---------------- RoPE cos/sin table: [SEQ][32] pairs ----------------
__global__ void k_rope_tab(float* __restrict__ tab) {
  int id = blockIdx.x * blockDim.x + threadIdx.x;
  if (id >= SEQ * 32) return;
  int s = id >> 5, i = id & 31;
  float inv = powf(10000.f, -(float)i / 32.f);
  float ang = (float)s * inv;
  float sn, cs;
  sincosf(ang, &sn, &cs);
  tab[id * 2] = cs;
  tab[id * 2 + 1] = sn;
}

// ---------------- V transpose: Y[b,s,h*64+d] -> VT[bh, d, s] ----------------
__global__ __launch_bounds__(256) void k_tr_v(const ushort* __restrict__ Y,
                                              ushort* __restrict__ VT) {
  __shared__ ushort tile[64][65];
  const int st = blockIdx.x, bh = blockIdx.y;
  const int b = bh >> 4, h = bh & 15;
  const int d = threadIdx.x & 63, s4 = threadIdx.x >> 6;
#pragma unroll
  for (int p = 0; p < 16; ++p) {
    int sl = p * 4 + s4;
    tile[d][sl] = Y[(size_t)(b * SEQ + st * 64 + sl) * DM + h * 64 + d];
  }
  __syncthreads();
  const int sl = threadIdx.x & 63, d4 = threadIdx.x >> 6;
#pragma unroll
  for (int p = 0; p < 16; ++p) {
    int dl = p * 4 + d4;
    VT[(size_t)bh * DK * SEQ + (size_t)dl * SEQ + st * 64 + sl] = tile[dl][sl];
  }
}

// ---------------- async global->LDS 16B ----------------
__device__ __forceinline__ void gll16(const void* g, void* l) {
  __builtin_amdgcn_global_load_lds((const __attribute__((address_space(1))) void*)g,
                                   (__attribute__((address_space(3))) void*)l, 16, 0, 0);
}

// ---------------- QKV GEMM: counted-vmcnt 2-deep pipeline + fused RoPE -------
#define GSTAGE(AD, BD, kk_) do {                                               \
    gll16(A + (size_t)(m0 + w * 16 + lrow) * K + (kk_) + lcol, (void*)((AD) + w * 512));        \
    gll16(A + (size_t)(m0 + 64 + w * 16 + lrow) * K + (kk_) + lcol, (void*)((AD) + 2048 + w * 512)); \
    gll16(Bw + (size_t)(n0 + w * 16 + lrow) * K + (kk_) + lcol, (void*)((BD) + w * 512));       \
    gll16(Bw + (size_t)(n0 + 64 + w * 16 + lrow) * K + (kk_) + lcol, (void*)((BD) + 2048 + w * 512)); \
  } while (0)

#define GCOMP(AS_, BS_) do {                                                   \
    bf16x8 af[4], bfr[4];                                                      \
    _Pragma("unroll")                                                          \
    for (int i = 0; i < 4; ++i)                                                \
      af[i] = *(const bf16x8*)((AS_) + (wr * 64 + i * 16 + l15) * 32 + l4 * 8);\
    _Pragma("unroll")                                                          \
    for (int i = 0; i < 4; ++i)                                                \
      bfr[i] = *(const bf16x8*)((BS_) + (wc * 64 + i * 16 + l15) * 32 + l4 * 8);\
    _Pragma("unroll")                                                          \
    for (int mi = 0; mi < 4; ++mi)                                             \
      _Pragma("unroll")                                                        \
      for (int ni = 0; ni < 4; ++ni)                                           \
        acc[mi][ni] = __builtin_amdgcn_mfma_f32_16x16x32_bf16(af[mi], bfr[ni], acc[mi][ni], 0, 0, 0); \
  } while (0)

// grid: flat 768.  id decode keeps same-m blocks on the same XCD (id%8 == m%8)
// so each XCD's A panels stay L2-resident; its 8 B tiles (2 MB) also fit L2.
__global__ __launch_bounds__(256) void k_gemm_qkv(const ushort* __restrict__ A,
                                                  const ushort* __restrict__ Bw,
                                                  ushort* __restrict__ qT,
                                                  ushort* __restrict__ kT,
                                                  ushort* __restrict__ YV,
                                                  const float* __restrict__ tab,
                                                  float qscale, int M, int N, int K) {
  const int id = blockIdx.x;
  const int mlo = id & 7, nb = (id >> 3) & 7, mhi = (id >> 6) & 3, z = id >> 8;
  const int m0 = (mhi * 8 + mlo) * 128, n0 = nb * 128;
  A += (size_t)z * ((size_t)M * K);
  Bw += (size_t)z * ((size_t)N * K);
  __shared__ ushort As0[128 * 32], Bs0[128 * 32];
  __shared__ ushort As1[128 * 32], Bs1[128 * 32];
  const int tid = threadIdx.x;
  const int w = tid >> 6, lane = tid & 63;
  const int l15 = lane & 15, l4 = lane >> 4;
  const int wr = w >> 1, wc = w & 1;
  const int lrow = lane >> 2, lcol = (lane & 3) * 8;
  f32x4 acc[4][4] = {};
  GSTAGE(As0, Bs0, 0);
  GSTAGE(As1, Bs1, 32);
  for (int kk = 0; kk < K - 64; kk += 64) {
    WAITV4; BARR();
    GCOMP(As0, Bs0);
    WAITL0; BARR();
    GSTAGE(As0, Bs0, kk + 64);
    WAITV4; BARR();
    GCOMP(As1, Bs1);
    WAITL0; BARR();
    if (kk + 96 < K) GSTAGE(As1, Bs1, kk + 96);
  }
  WAITV4; BARR();
  GCOMP(As0, Bs0);
  WAITV0; BARR();
  GCOMP(As1, Bs1);
  if (z == 2) {
#pragma unroll
    for (int mi = 0; mi < 4; ++mi)
#pragma unroll
      for (int ni = 0; ni < 4; ++ni)
#pragma unroll
        for (int r = 0; r < 4; ++r) {
          int row = m0 + wr * 64 + mi * 16 + l4 * 4 + r;
          int col = n0 + wc * 64 + ni * 16 + l15;
          YV[(size_t)row * N + col] = f2bf(acc[mi][ni][r]);
        }
  } else {
    const float scale = (z == 0) ? qscale : 1.0f;
    ushort* T = (z == 0) ? qT : kT;
    const bool odd = (l15 & 1);
#pragma unroll
    for (int mi = 0; mi < 4; ++mi)
#pragma unroll
      for (int ni = 0; ni < 4; ++ni)
#pragma unroll
        for (int r = 0; r < 4; ++r) {
          int row = m0 + wr * 64 + mi * 16 + l4 * 4 + r;
          int col = n0 + wc * 64 + ni * 16 + l15;
          float v = acc[mi][ni][r];
          float pv = __shfl_xor(v, 1);
          int s = row & (SEQ - 1);
          int d = col & 63;
          float2 cs = *(const float2*)(tab + ((size_t)s * 32 + (d >> 1)) * 2);
          float xe = odd ? pv : v, xo = odd ? v : pv;
          float outv = (odd ? (xe * cs.y + xo * cs.x) : (xe * cs.x - xo * cs.y)) * scale;
          int bh = (row >> 11) * 16 + (col >> 6);
          T[((size_t)bh * SEQ + s) * 64 + d] = f2bf(outv);
        }
  }
}

// ---------------- final GEMM: counted-vmcnt 2-deep pipeline, fp32 out --------
#define FSTAGE(AD, BD, kk_) do {                                               \
    gll16(A + (size_t)(m0 + srow) * K + (kk_) + scol, (void*)((AD) + w * 512));\
    gll16(Bw + (size_t)(n0 + srow) * K + (kk_) + scol, (void*)((BD) + w * 512));\
    gll16(Bw + (size_t)(n0 + 64 + srow) * K + (kk_) + scol, (void*)((BD) + 2048 + w * 512)); \
  } while (0)

#define FCOMP(AS_, BS_) do {                                                   \
    bf16x8 af[2], bfr[4];                                                      \
    _Pragma("unroll")                                                          \
    for (int i = 0; i < 2; ++i)                                                \
      af[i] = *(const bf16x8*)((AS_) + (wr * 32 + i * 16 + l15) * 32 + l4 * 8);\
    _Pragma("unroll")                                                          \
    for (int i = 0; i < 4; ++i)                                                \
      bfr[i] = *(const bf16x8*)((BS_) + (wc * 64 + i * 16 + l15) * 32 + l4 * 8);\
    _Pragma("unroll")                                                          \
    for (int mi = 0; mi < 2; ++mi)                                             \
      _Pragma("unroll")                                                        \
      for (int ni = 0; ni < 4; ++ni)                                           \
        acc[mi][ni] = __builtin_amdgcn_mfma_f32_16x16x32_bf16(af[mi], bfr[ni], acc[mi][ni], 0, 0, 0); \
  } while (0)

// grid: flat 512; id%8 == m%8 (XCD-local A panels)
__global__ __launch_bounds__(256) void k_gemm_f(const ushort* __restrict__ A,
                                                const ushort* __restrict__ Bw,
                                                float* __restrict__ C, int M, int N, int K) {
  const int id = blockIdx.x;
  const int mlo = id & 7, nb = (id >> 3) & 7, mhi = id >> 6;
  const int m0 = (mhi * 8 + mlo) * 64, n0 = nb * 128;
  __shared__ ushort As0[64 * 32], Bs0[128 * 32];
  __shared__ ushort As1[64 * 32], Bs1[128 * 32];
  const int tid = threadIdx.x;
  const int w = tid >> 6, lane = tid & 63;
  const int l15 = lane & 15, l4 = lane >> 4;
  const int wr = w >> 1, wc = w & 1;
  const int srow = tid >> 2, scol = (tid & 3) * 8;
  f32x4 acc[2][4] = {};
  FSTAGE(As0, Bs0, 0);
  FSTAGE(As1, Bs1, 32);
  for (int kk = 0; kk < K - 64; kk += 64) {
    WAITV3; BARR();
    FCOMP(As0, Bs0);
    WAITL0; BARR();
    FSTAGE(As0, Bs0, kk + 64);
    WAITV3; BARR();
    FCOMP(As1, Bs1);
    WAITL0; BARR();
    if (kk + 96 < K) FSTAGE(As1, Bs1, kk + 96);
  }
  WAITV3; BARR();
  FCOMP(As0, Bs0);
  WAITV0; BARR();
  FCOMP(As1, Bs1);
#pragma unroll
  for (int mi = 0; mi < 2; ++mi)
#pragma unroll
    for (int ni = 0; ni < 4; ++ni)
#pragma unroll
      for (int r = 0; r < 4; ++r) {
        int row = m0 + wr * 32 + mi * 16 + l4 * 4 + r;
        int col = n0 + wc * 64 + ni * 16 + l15;
        C[(size_t)row * N + col] = acc[mi][ni][r];
      }
}

// ---------------- causal flash attention: QBLK=128, 2 strips/wave ------------
#define STAGE1(DST, src, srcstride) do {                                       \
    _Pragma("unroll")                                                          \
    for (int i_ = 0; i_ < 2; ++i_) {                                           \
      int tt_ = i_ * 256 + tid;                                                \
      int row_ = tt_ >> 3, c_ = (tt_ & 7) ^ (row_ & 7);                        \
      gll16(src + (size_t)row_ * (srcstride) + c_ * 8,                         \
            (void*)((char*)(DST) + (i_ * 256 + w * 64) * 16));                 \
    }                                                                          \
  } while (0)

#define STAGE(KD, VD, kt_) do {                                                \
    const ushort* kb_ = kT + hb + (size_t)(kt_) * 4096;                        \
    const ushort* vb_ = vT + vbase + (size_t)(kt_) * 64;                       \
    STAGE1(KD, kb_, 64);                                                       \
    STAGE1(VD, vb_, SEQ);                                                      \
  } while (0)

#define LDSFRAG(BASE, row_, cidx)                                              \
  (*(const bf16x8*)((const char*)(BASE) + (row_) * 128 + (((cidx) ^ (l15 & 7)) * 16)))

#define SMAXUPD(P, MRUN, LRUN, SO) do {                                        \
    float a0 = fmaxf(fmaxf(P[0][0], P[0][1]), fmaxf(P[0][2], P[0][3]));        \
    float a1 = fmaxf(fmaxf(P[1][0], P[1][1]), fmaxf(P[1][2], P[1][3]));        \
    float a2 = fmaxf(fmaxf(P[2][0], P[2][1]), fmaxf(P[2][2], P[2][3]));        \
    float a3 = fmaxf(fmaxf(P[3][0], P[3][1]), fmaxf(P[3][2], P[3][3]));        \
    float mx = fmaxf(fmaxf(a0, a1), fmaxf(a2, a3));                            \
    mx = fmaxf(mx, __shfl_xor(mx, 16));                                        \
    mx = fmaxf(mx, __shfl_xor(mx, 32));                                        \
    const float mn = fmaxf(MRUN, mx);                                          \
    SO = __builtin_amdgcn_exp2f(MRUN - mn);                                    \
    float rs = 0.f;                                                            \
    _Pragma("unroll")                                                          \
    for (int nf = 0; nf < 4; ++nf) {                                           \
      float e0 = __builtin_amdgcn_exp2f(P[nf][0] - mn);                        \
      float e1 = __builtin_amdgcn_exp2f(P[nf][1] - mn);                        \
      float e2 = __builtin_amdgcn_exp2f(P[nf][2] - mn);                        \
      float e3 = __builtin_amdgcn_exp2f(P[nf][3] - mn);                        \
      P[nf][0] = e0; P[nf][1] = e1; P[nf][2] = e2; P[nf][3] = e3;              \
      rs += (e0 + e1) + (e2 + e3);                                             \
    }                                                                          \
    rs += __shfl_xor(rs, 16);                                                  \
    rs += __shfl_xor(rs, 32);                                                  \
    LRUN = LRUN * SO + rs;                                                     \
    MRUN = mn;                                                                 \
  } while (0)

#define RESCALE(ACC, SO) do {                                                  \
    float soq[4];                                                              \
    _Pragma("unroll")                                                          \
    for (int r = 0; r < 4; ++r) soq[r] = __shfl(SO, l4 * 4 + r);               \
    _Pragma("unroll")                                                          \
    for (int df = 0; df < 4; ++df)                                             \
      _Pragma("unroll")                                                        \
      for (int r = 0; r < 4; ++r) ACC[df][r] *= soq[r];                        \
  } while (0)

#define PWRITE(P, MYP) do {                                                    \
    _Pragma("unroll")                                                          \
    for (int nf = 0; nf < 4; ++nf) {                                           \
      uint2 pk;                                                                \
      pk.x = cvtpk(P[nf][0], P[nf][1]);                                        \
      pk.y = cvtpk(P[nf][2], P[nf][3]);                                        \
      *(uint2*)((MYP) + ((l15 * 128 + nf * 32 + l4 * 8) ^ swz)) = pk;          \
    }                                                                          \
  } while (0)

#define STEP2(KC, VC, KN, VN, kt_, M0, M1, PREF) do {                          \
    if (PREF) { STAGE(KN, VN, (kt_) + 1); }                                    \
    float p0[4][4], p1[4][4];                                                  \
    _Pragma("unroll")                                                          \
    for (int nf = 0; nf < 4; ++nf) {                                           \
      bf16x8 k0_ = LDSFRAG(KC, nf * 16 + l15, l4);                             \
      bf16x8 k1_ = LDSFRAG(KC, nf * 16 + l15, l4 + 4);                         \
      if (M0 >= 0) {                                                           \
        f32x4 z = {0.f, 0.f, 0.f, 0.f};                                        \
        z = __builtin_amdgcn_mfma_f32_16x16x32_bf16(k0_, qb00, z, 0, 0, 0);    \
        z = __builtin_amdgcn_mfma_f32_16x16x32_bf16(k1_, qb01, z, 0, 0, 0);    \
        _Pragma("unroll")                                                      \
        for (int r = 0; r < 4; ++r) {                                          \
          float sc = z[r];                                                     \
          if (M0 == 1 && (nf * 16 + l4 * 4 + r) > (w * 16 + l15)) sc = -INFINITY; \
          p0[nf][r] = sc;                                                      \
        }                                                                      \
      }                                                                        \
      {                                                                        \
        f32x4 z = {0.f, 0.f, 0.f, 0.f};                                        \
        z = __builtin_amdgcn_mfma_f32_16x16x32_bf16(k0_, qb10, z, 0, 0, 0);    \
        z = __builtin_amdgcn_mfma_f32_16x16x32_bf16(k1_, qb11, z, 0, 0, 0);    \
        _Pragma("unroll")                                                      \
        for (int r = 0; r < 4; ++r) {                                          \
          float sc = z[r];                                                     \
          if (M1 == 1 && (nf * 16 + l4 * 4 + r) > (w * 16 + l15)) sc = -INFINITY; \
          p1[nf][r] = sc;                                                      \
        }                                                                      \
      }                                                                        \
    }                                                                          \
    float so0_, so1_;                                                          \
    if (M0 >= 0) { SMAXUPD(p0, mrun0, lrun0, so0_); RESCALE(acc0, so0_); PWRITE(p0, myP0); } \
    SMAXUPD(p1, mrun1, lrun1, so1_); RESCALE(acc1, so1_); PWRITE(p1, myP1);    \
    bf16x8 pa00, pa01, pa10, pa11;                                             \
    if (M0 >= 0) {                                                             \
      pa00 = *(const bf16x8*)(myP0 + ((l15 * 128 + l4 * 16) ^ swz));           \
      pa01 = *(const bf16x8*)(myP0 + ((l15 * 128 + 64 + l4 * 16) ^ swz));      \
    }                                                                          \
    pa10 = *(const bf16x8*)(myP1 + ((l15 * 128 + l4 * 16) ^ swz));             \
    pa11 = *(const bf16x8*)(myP1 + ((l15 * 128 + 64 + l4 * 16) ^ swz));        \
    _Pragma("unroll")                                                          \
    for (int df = 0; df < 4; ++df) {                                           \
      bf16x8 v0_ = LDSFRAG(VC, df * 16 + l15, l4);                             \
      bf16x8 v1_ = LDSFRAG(VC, df * 16 + l15, l4 + 4);                         \
      if (M0 >= 0) {                                                           \
        acc0[df] = __builtin_amdgcn_mfma_f32_16x16x32_bf16(pa00, v0_, acc0[df], 0, 0, 0); \
        acc0[df] = __builtin_amdgcn_mfma_f32_16x16x32_bf16(pa01, v1_, acc0[df], 0, 0, 0); \
      }                                                                        \
      acc1[df] = __builtin_amdgcn_mfma_f32_16x16x32_bf16(pa10, v0_, acc1[df], 0, 0, 0); \
      acc1[df] = __builtin_amdgcn_mfma_f32_16x16x32_bf16(pa11, v1_, acc1[df], 0, 0, 0); \
    }                                                                          \
    __syncthreads();                                                           \
  } while (0)

__global__ __launch_bounds__(256, 3) void k_flash(const ushort* __restrict__ qT,
                                                  const ushort* __restrict__ kT,
                                                  const ushort* __restrict__ vT,
                                                  ushort* __restrict__ AO) {
  __shared__ ushort Ks[2][64 * 64];
  __shared__ ushort Vs[2][64 * 64];
  __shared__ char Plds[4 * 4096];
  const int l = blockIdx.x;
  const int bh = (l & 7) * 4 + ((l >> 3) & 3);
  const int qt = (SEQ / 128 - 1) - (l >> 5);
  const int tid = threadIdx.x, w = tid >> 6, lane = tid & 63;
  const int l15 = lane & 15, l4 = lane >> 4;
  const size_t hb = (size_t)bh * SEQ * DK;
  const size_t vbase = (size_t)bh * DK * SEQ;
  const int qrow0 = qt * 128 + w * 16;
  const int qrow1 = qrow0 + 64;
  const bf16x8 qb00 = *(const bf16x8*)(qT + hb + (size_t)(qrow0 + l15) * 64 + l4 * 8);
  const bf16x8 qb01 = *(const bf16x8*)(qT + hb + (size_t)(qrow0 + l15) * 64 + 32 + l4 * 8);
  const bf16x8 qb10 = *(const bf16x8*)(qT + hb + (size_t)(qrow1 + l15) * 64 + l4 * 8);
  const bf16x8 qb11 = *(const bf16x8*)(qT + hb + (size_t)(qrow1 + l15) * 64 + 32 + l4 * 8);
  f32x4 acc0[4] = {}, acc1[4] = {};
  float mrun0 = -INFINITY, lrun0 = 0.f, mrun1 = -INFINITY, lrun1 = 0.f;
  char* myP0 = (char*)Plds + w * 4096;
  char* myP1 = myP0 + 2048;
  const int swz = (l15 & 7) << 4;
  ushort* kc = &Ks[0][0]; ushort* vc = &Vs[0][0];
  ushort* kn = &Ks[1][0]; ushort* vn = &Vs[1][0];
  STAGE(kc, vc, 0);
  __syncthreads();
  for (int kt = 0; kt < 2 * qt; ++kt) {
    STEP2(kc, vc, kn, vn, kt, 0, 0, true);
    ushort* t;
    t = kc; kc = kn; kn = t;
    t = vc; vc = vn; vn = t;
  }
  STEP2(kc, vc, kn, vn, 2 * qt, 1, 0, true);
  {
    ushort* t;
    t = kc; kc = kn; kn = t;
    t = vc; vc = vn; vn = t;
  }
  STEP2(kc, vc, kn, vn, 2 * qt + 1, -1, 1, false);
  const int b = bh >> 4, h = bh & 15;
  float lq0[4], lq1[4];
#pragma unroll
  for (int r = 0; r < 4; ++r) {
    lq0[r] = __shfl(lrun0, l4 * 4 + r);
    lq1[r] = __shfl(lrun1, l4 * 4 + r);
  }
#pragma unroll
  for (int r = 0; r < 4; ++r) {
    float inv0 = 1.f / lq0[r], inv1 = 1.f / lq1[r];
    int qr0 = qrow0 + l4 * 4 + r, qr1 = qrow1 + l4 * 4 + r;
#pragma unroll
    for (int df = 0; df < 4; ++df) {
      AO[(size_t)(b * SEQ + qr0) * DM + h * 64 + df * 16 + l15] = f2bf(acc0[df][r] * inv0);
      AO[(size_t)(b * SEQ + qr1) * DM + h * 64 + df * 16 + l15] = f2bf(acc1[df][r] * inv1);
    }
  }
}

extern "C" void kernel_launch(void* const* d_in, const int* in_sizes, int n_in,
                              void* d_out, int out_size, void* d_ws, size_t ws_size,
                              hipStream_t stream) {
  const float* Q = (const float*)d_in[0];
  const float* K = (const float*)d_in[1];
  const float* V = (const float*)d_in[2];
  const float* wq = (const float*)d_in[3];
  const float* wk = (const float*)d_in[4];
  const float* wv = (const float*)d_in[5];
  const float* wo = (const float*)d_in[6];
  float* out = (float*)d_out;
  char* ws = (char*)d_ws;

  ushort* XQ = (ushort*)(ws + 0);          // 8 MB each, XQ/XK/XV contiguous
  ushort* XK = (ushort*)(ws + 8388608);
  ushort* WQ = (ushort*)(ws + 25165824);   // 2 MB each, WQ..WO contiguous
  ushort* qT = (ushort*)(ws + 33554432);   // 8 MB
  ushort* kT = (ushort*)(ws + 41943040);   // 8 MB
  ushort* YV = (ushort*)(ws + 50331648);   // 8 MB
  float* TAB = (float*)(ws + 58720256);    // 512 KB
  // stream-ordered reuse:
  ushort* vT = XQ;   // tr_v output (XQ consumed by gemm_qkv)
  ushort* AO = XK;   // flash output (XK consumed by gemm_qkv)

  const int NX4 = BATCH * SEQ * DM / 4;
  const int NW4 = DM * DM / 4;
  P4 xin = {Q, K, V, nullptr};
  P4 win = {wq, wk, wv, wo};
  k_castN<<<dim3(1024, 1, 3), 256, 0, stream>>>(xin, XQ, NX4);
  k_castN<<<dim3(1024, 1, 4), 256, 0, stream>>>(win, WQ, NW4);
  k_rope_tab<<<(SEQ * 32) / 256, 256, 0, stream>>>(TAB);

  const float QSCALE = 0.125f * 1.4426950408889634f;  // 1/sqrt(dk) * log2(e)
  k_gemm_qkv<<<768, 256, 0, stream>>>(XQ, WQ, qT, kT, YV, TAB, QSCALE,
                                      BATCH * SEQ, DM, DM);

  k_tr_v<<<dim3(SEQ / 64, BH), 256, 0, stream>>>(YV, vT);

  k_flash<<<BH * (SEQ / 128), 256, 0, stream>>>(qT, kT, vT, AO);

  k_gemm_f<<<512, 256, 0, stream>>>(AO, WQ + 3 * DM * DM, out, BATCH * SEQ, DM, DM);
}

// Round 9
// 127.038 us; speedup vs baseline: 1.8743x; 1.0252x over previous
//
#include <hip/hip_runtime.h>

#define SEQ 2048
#define BATCH 2
#define DM 1024
#define NH 16
#define DK 64
#define BH (BATCH*NH)

typedef __attribute__((ext_vector_type(8))) short bf16x8;
typedef __attribute__((ext_vector_type(4))) float f32x4;

__device__ __forceinline__ ushort f2bf(float f) {
  union { float f; unsigned u; } v; v.f = f;
  unsigned r = (v.u + 0x7fffu + ((v.u >> 16) & 1u)) >> 16;
  return (ushort)r;
}
__device__ __forceinline__ float bf2f(ushort h) {
  union { unsigned u; float f; } v; v.u = ((unsigned)h) << 16;
  return v.f;
}
__device__ __forceinline__ unsigned cvtpk(float lo, float hi) {
  unsigned r;
  asm("v_cvt_pk_bf16_f32 %0, %1, %2" : "=v"(r) : "v"(lo), "v"(hi));
  return r;
}

// counted-vmcnt sync primitives (T4)
#define WAITV4 asm volatile("s_waitcnt vmcnt(4)" ::: "memory")
#define WAITV3 asm volatile("s_waitcnt vmcnt(3)" ::: "memory")
#define WAITV0 asm volatile("s_waitcnt vmcnt(0)" ::: "memory")
#define WAITL0 asm volatile("s_waitcnt lgkmcnt(0)" ::: "memory")
#define BARR() __builtin_amdgcn_s_barrier()

// ---------------- batched cast fp32 -> bf16 (z = tensor index) ----------------
struct P4 { const float* p0; const float* p1; const float* p2; const float* p3; };
__global__ void k_castN(P4 in, ushort* __restrict__ out, int n4) {
  const float* src = (blockIdx.z == 0) ? in.p0 : (blockIdx.z == 1) ? in.p1
                    : (blockIdx.z == 2) ? in.p2 : in.p3;
  ushort* dst = out + (size_t)blockIdx.z * (size_t)n4 * 4;
  int i = blockIdx.x * blockDim.x + threadIdx.x;
  int st = gridDim.x * blockDim.x;
  for (; i < n4; i += st) {
    float4 v = reinterpret_cast<const float4*>(src)[i];
    ushort4 o;
    o.x = f2bf(v.x); o.y = f2bf(v.y); o.z = f2bf(v.z); o.w = f2bf(v.w);
    reinterpret_cast<ushort4*>(dst)[i] = o;
  }
}

// ---------------- RoPE cos/sin table: [SEQ][32] pairs ----------------
__global__ void k_rope_tab(float* __restrict__ tab) {
  int id = blockIdx.x * blockDim.x + threadIdx.x;
  if (id >= SEQ * 32) return;
  int s = id >> 5, i = id & 31;
  float inv = powf(10000.f, -(float)i / 32.f);
  float ang = (float)s * inv;
  float sn, cs;
  sincosf(ang, &sn, &cs);
  tab[id * 2] = cs;
  tab[id * 2 + 1] = sn;
}

// ---------------- V transpose: Y[b,s,h*64+d] -> VT[bh, d, s] ----------------
__global__ __launch_bounds__(256) void k_tr_v(const ushort* __restrict__ Y,
                                              ushort* __restrict__ VT) {
  __shared__ ushort tile[64][65];
  const int st = blockIdx.x, bh = blockIdx.y;
  const int b = bh >> 4, h = bh & 15;
  const int d = threadIdx.x & 63, s4 = threadIdx.x >> 6;
#pragma unroll
  for (int p = 0; p < 16; ++p) {
    int sl = p * 4 + s4;
    tile[d][sl] = Y[(size_t)(b * SEQ + st * 64 + sl) * DM + h * 64 + d];
  }
  __syncthreads();
  const int sl = threadIdx.x & 63, d4 = threadIdx.x >> 6;
#pragma unroll
  for (int p = 0; p < 16; ++p) {
    int dl = p * 4 + d4;
    VT[(size_t)bh * DK * SEQ + (size_t)dl * SEQ + st * 64 + sl] = tile[dl][sl];
  }
}

// ---------------- async global->LDS 16B ----------------
__device__ __forceinline__ void gll16(const void* g, void* l) {
  __builtin_amdgcn_global_load_lds((const __attribute__((address_space(1))) void*)g,
                                   (__attribute__((address_space(3))) void*)l, 16, 0, 0);
}

// ---------------- QKV GEMM: counted-vmcnt 2-deep pipeline + fused RoPE -------
#define GSTAGE(AD, BD, kk_) do {                                               \
    gll16(A + (size_t)(m0 + w * 16 + lrow) * K + (kk_) + lcol, (void*)((AD) + w * 512));        \
    gll16(A + (size_t)(m0 + 64 + w * 16 + lrow) * K + (kk_) + lcol, (void*)((AD) + 2048 + w * 512)); \
    gll16(Bw + (size_t)(n0 + w * 16 + lrow) * K + (kk_) + lcol, (void*)((BD) + w * 512));       \
    gll16(Bw + (size_t)(n0 + 64 + w * 16 + lrow) * K + (kk_) + lcol, (void*)((BD) + 2048 + w * 512)); \
  } while (0)

#define GCOMP(AS_, BS_) do {                                                   \
    bf16x8 af[4], bfr[4];                                                      \
    _Pragma("unroll")                                                          \
    for (int i = 0; i < 4; ++i)                                                \
      af[i] = *(const bf16x8*)((AS_) + (wr * 64 + i * 16 + l15) * 32 + l4 * 8);\
    _Pragma("unroll")                                                          \
    for (int i = 0; i < 4; ++i)                                                \
      bfr[i] = *(const bf16x8*)((BS_) + (wc * 64 + i * 16 + l15) * 32 + l4 * 8);\
    _Pragma("unroll")                                                          \
    for (int mi = 0; mi < 4; ++mi)                                             \
      _Pragma("unroll")                                                        \
      for (int ni = 0; ni < 4; ++ni)                                           \
        acc[mi][ni] = __builtin_amdgcn_mfma_f32_16x16x32_bf16(af[mi], bfr[ni], acc[mi][ni], 0, 0, 0); \
  } while (0)

// grid: flat 768.  id%8 == m%8 -> XCD-local A panels + L2-resident B tiles.
__global__ __launch_bounds__(256) void k_gemm_qkv(const ushort* __restrict__ A,
                                                  const ushort* __restrict__ Bw,
                                                  ushort* __restrict__ qT,
                                                  ushort* __restrict__ kT,
                                                  ushort* __restrict__ YV,
                                                  const float* __restrict__ tab,
                                                  float qscale, int M, int N, int K) {
  const int id = blockIdx.x;
  const int mlo = id & 7, nb = (id >> 3) & 7, mhi = (id >> 6) & 3, z = id >> 8;
  const int m0 = (mhi * 8 + mlo) * 128, n0 = nb * 128;
  A += (size_t)z * ((size_t)M * K);
  Bw += (size_t)z * ((size_t)N * K);
  __shared__ ushort As0[128 * 32], Bs0[128 * 32];
  __shared__ ushort As1[128 * 32], Bs1[128 * 32];
  const int tid = threadIdx.x;
  const int w = tid >> 6, lane = tid & 63;
  const int l15 = lane & 15, l4 = lane >> 4;
  const int wr = w >> 1, wc = w & 1;
  const int lrow = lane >> 2, lcol = (lane & 3) * 8;
  f32x4 acc[4][4] = {};
  GSTAGE(As0, Bs0, 0);
  GSTAGE(As1, Bs1, 32);
  for (int kk = 0; kk < K - 64; kk += 64) {
    WAITV4; BARR();
    GCOMP(As0, Bs0);
    WAITL0; BARR();
    GSTAGE(As0, Bs0, kk + 64);
    WAITV4; BARR();
    GCOMP(As1, Bs1);
    WAITL0; BARR();
    if (kk + 96 < K) GSTAGE(As1, Bs1, kk + 96);
  }
  WAITV4; BARR();
  GCOMP(As0, Bs0);
  WAITV0; BARR();
  GCOMP(As1, Bs1);
  if (z == 2) {
#pragma unroll
    for (int mi = 0; mi < 4; ++mi)
#pragma unroll
      for (int ni = 0; ni < 4; ++ni)
#pragma unroll
        for (int r = 0; r < 4; ++r) {
          int row = m0 + wr * 64 + mi * 16 + l4 * 4 + r;
          int col = n0 + wc * 64 + ni * 16 + l15;
          YV[(size_t)row * N + col] = f2bf(acc[mi][ni][r]);
        }
  } else {
    const float scale = (z == 0) ? qscale : 1.0f;
    ushort* T = (z == 0) ? qT : kT;
    const bool odd = (l15 & 1);
#pragma unroll
    for (int mi = 0; mi < 4; ++mi)
#pragma unroll
      for (int ni = 0; ni < 4; ++ni)
#pragma unroll
        for (int r = 0; r < 4; ++r) {
          int row = m0 + wr * 64 + mi * 16 + l4 * 4 + r;
          int col = n0 + wc * 64 + ni * 16 + l15;
          float v = acc[mi][ni][r];
          float pv = __shfl_xor(v, 1);
          int s = row & (SEQ - 1);
          int d = col & 63;
          float2 cs = *(const float2*)(tab + ((size_t)s * 32 + (d >> 1)) * 2);
          float xe = odd ? pv : v, xo = odd ? v : pv;
          float outv = (odd ? (xe * cs.y + xo * cs.x) : (xe * cs.x - xo * cs.y)) * scale;
          int bh = (row >> 11) * 16 + (col >> 6);
          T[((size_t)bh * SEQ + s) * 64 + d] = f2bf(outv);
        }
  }
}

// ---------------- final GEMM: counted-vmcnt 2-deep pipeline, fp32 out --------
#define FSTAGE(AD, BD, kk_) do {                                               \
    gll16(A + (size_t)(m0 + srow) * K + (kk_) + scol, (void*)((AD) + w * 512));\
    gll16(Bw + (size_t)(n0 + srow) * K + (kk_) + scol, (void*)((BD) + w * 512));\
    gll16(Bw + (size_t)(n0 + 64 + srow) * K + (kk_) + scol, (void*)((BD) + 2048 + w * 512)); \
  } while (0)

#define FCOMP(AS_, BS_) do {                                                   \
    bf16x8 af[2], bfr[4];                                                      \
    _Pragma("unroll")                                                          \
    for (int i = 0; i < 2; ++i)                                                \
      af[i] = *(const bf16x8*)((AS_) + (wr * 32 + i * 16 + l15) * 32 + l4 * 8);\
    _Pragma("unroll")                                                          \
    for (int i = 0; i < 4; ++i)                                                \
      bfr[i] = *(const bf16x8*)((BS_) + (wc * 64 + i * 16 + l15) * 32 + l4 * 8);\
    _Pragma("unroll")                                                          \
    for (int mi = 0; mi < 2; ++mi)                                             \
      _Pragma("unroll")                                                        \
      for (int ni = 0; ni < 4; ++ni)                                           \
        acc[mi][ni] = __builtin_amdgcn_mfma_f32_16x16x32_bf16(af[mi], bfr[ni], acc[mi][ni], 0, 0, 0); \
  } while (0)

__global__ __launch_bounds__(256) void k_gemm_f(const ushort* __restrict__ A,
                                                const ushort* __restrict__ Bw,
                                                float* __restrict__ C, int M, int N, int K) {
  const int id = blockIdx.x;
  const int mlo = id & 7, nb = (id >> 3) & 7, mhi = id >> 6;
  const int m0 = (mhi * 8 + mlo) * 64, n0 = nb * 128;
  __shared__ ushort As0[64 * 32], Bs0[128 * 32];
  __shared__ ushort As1[64 * 32], Bs1[128 * 32];
  const int tid = threadIdx.x;
  const int w = tid >> 6, lane = tid & 63;
  const int l15 = lane & 15, l4 = lane >> 4;
  const int wr = w >> 1, wc = w & 1;
  const int srow = tid >> 2, scol = (tid & 3) * 8;
  f32x4 acc[2][4] = {};
  FSTAGE(As0, Bs0, 0);
  FSTAGE(As1, Bs1, 32);
  for (int kk = 0; kk < K - 64; kk += 64) {
    WAITV3; BARR();
    FCOMP(As0, Bs0);
    WAITL0; BARR();
    FSTAGE(As0, Bs0, kk + 64);
    WAITV3; BARR();
    FCOMP(As1, Bs1);
    WAITL0; BARR();
    if (kk + 96 < K) FSTAGE(As1, Bs1, kk + 96);
  }
  WAITV3; BARR();
  FCOMP(As0, Bs0);
  WAITV0; BARR();
  FCOMP(As1, Bs1);
#pragma unroll
  for (int mi = 0; mi < 2; ++mi)
#pragma unroll
    for (int ni = 0; ni < 4; ++ni)
#pragma unroll
      for (int r = 0; r < 4; ++r) {
        int row = m0 + wr * 32 + mi * 16 + l4 * 4 + r;
        int col = n0 + wc * 64 + ni * 16 + l15;
        C[(size_t)row * N + col] = acc[mi][ni][r];
      }
}

// ---------------- causal flash attention: QBLK=128, KVBLK=128 ----------------
// qT (pre-scaled by 0.125*log2e), kT: [bh,s,64]  vT: [bh,64,s]  AO: [b,s,h*64+d]
// Per step: 128 k. K tile [128][64] (8B-chunks swz ^row&7); V tile [64][128]
// (16B-chunks swz ^row&15). PV in two 64-k halves through wave-private 2KB P
// (DS in-order per wave -> no sync). Deferred l-reduction; defer-max rescale.
#define KSTAGE(DST, kt_) do {                                                  \
    const ushort* kb_ = kT + hb + (size_t)(kt_) * 8192;                        \
    _Pragma("unroll")                                                          \
    for (int i_ = 0; i_ < 4; ++i_) {                                           \
      int tt_ = i_ * 256 + tid;                                                \
      int row_ = tt_ >> 3, c_ = (tt_ & 7) ^ (row_ & 7);                        \
      gll16(kb_ + (size_t)row_ * 64 + c_ * 8,                                  \
            (void*)((char*)(DST) + (i_ * 256 + w * 64) * 16));                 \
    }                                                                          \
  } while (0)

#define VSTAGE(DST, kt_) do {                                                  \
    const ushort* vb_ = vT + vbase + (size_t)(kt_) * 128;                      \
    _Pragma("unroll")                                                          \
    for (int i_ = 0; i_ < 4; ++i_) {                                           \
      int tt_ = i_ * 256 + tid;                                                \
      int row_ = tt_ >> 4, c_ = (tt_ & 15) ^ (row_ & 15);                      \
      gll16(vb_ + (size_t)row_ * SEQ + c_ * 8,                                 \
            (void*)((char*)(DST) + (i_ * 256 + w * 64) * 16));                 \
    }                                                                          \
  } while (0)

#define FRK(BASE, row_, cidx)                                                  \
  (*(const bf16x8*)((const char*)(BASE) + (row_) * 128 + ((((cidx) ^ ((row_) & 7)) & 7) * 16)))
#define FRV(BASE, row_, cidx)                                                  \
  (*(const bf16x8*)((const char*)(BASE) + (row_) * 256 + ((((cidx) ^ ((row_) & 15)) & 15) * 16)))

// softmax over 8 frags; deferred sum (lrun stays lane-partial); defer-max
#define SMAX8(P, MRUN, LRUN, ACC) do {                                         \
    float mx = P[0][0];                                                        \
    _Pragma("unroll")                                                          \
    for (int nf = 0; nf < 8; ++nf)                                             \
      _Pragma("unroll")                                                        \
      for (int r = 0; r < 4; ++r) mx = fmaxf(mx, P[nf][r]);                    \
    mx = fmaxf(mx, __shfl_xor(mx, 16));                                        \
    mx = fmaxf(mx, __shfl_xor(mx, 32));                                        \
    if (!__all(mx <= MRUN)) {                                                  \
      const float mn = fmaxf(MRUN, mx);                                        \
      const float so = __builtin_amdgcn_exp2f(MRUN - mn);                      \
      float soq[4];                                                            \
      _Pragma("unroll")                                                        \
      for (int r = 0; r < 4; ++r) soq[r] = __shfl(so, l4 * 4 + r);             \
      _Pragma("unroll")                                                        \
      for (int df = 0; df < 4; ++df)                                           \
        _Pragma("unroll")                                                      \
        for (int r = 0; r < 4; ++r) ACC[df][r] *= soq[r];                      \
      LRUN *= so;                                                              \
      MRUN = mn;                                                               \
    }                                                                          \
    float rs = 0.f;                                                            \
    _Pragma("unroll")                                                          \
    for (int nf = 0; nf < 8; ++nf) {                                           \
      float e0 = __builtin_amdgcn_exp2f(P[nf][0] - MRUN);                      \
      float e1 = __builtin_amdgcn_exp2f(P[nf][1] - MRUN);                      \
      float e2 = __builtin_amdgcn_exp2f(P[nf][2] - MRUN);                      \
      float e3 = __builtin_amdgcn_exp2f(P[nf][3] - MRUN);                      \
      P[nf][0] = e0; P[nf][1] = e1; P[nf][2] = e2; P[nf][3] = e3;              \
      rs += (e0 + e1) + (e2 + e3);                                             \
    }                                                                          \
    LRUN += rs;                                                                \
  } while (0)

// PV for one 64-k half H of strip P through its 2KB buffer MYP
#define PVHALF(P, MYP, ACC, VC, H) do {                                        \
    _Pragma("unroll")                                                          \
    for (int i = 0; i < 4; ++i) {                                              \
      uint2 pk;                                                                \
      pk.x = cvtpk(P[(H) * 4 + i][0], P[(H) * 4 + i][1]);                      \
      pk.y = cvtpk(P[(H) * 4 + i][2], P[(H) * 4 + i][3]);                      \
      *(uint2*)((MYP) + ((l15 * 128 + i * 32 + l4 * 8) ^ swz)) = pk;           \
    }                                                                          \
    const bf16x8 pa0 = *(const bf16x8*)((MYP) + ((l15 * 128 + l4 * 16) ^ swz));\
    const bf16x8 pa1 = *(const bf16x8*)((MYP) + ((l15 * 128 + 64 + l4 * 16) ^ swz));\
    _Pragma("unroll")                                                          \
    for (int df = 0; df < 4; ++df) {                                           \
      bf16x8 v0_ = FRV(VC, df * 16 + l15, (H) * 8 + l4);                       \
      bf16x8 v1_ = FRV(VC, df * 16 + l15, (H) * 8 + l4 + 4);                   \
      ACC[df] = __builtin_amdgcn_mfma_f32_16x16x32_bf16(pa0, v0_, ACC[df], 0, 0, 0); \
      ACC[df] = __builtin_amdgcn_mfma_f32_16x16x32_bf16(pa1, v1_, ACC[df], 0, 0, 0); \
    }                                                                          \
  } while (0)

#define STEP(KC, VC, KN, VN, kt_, DIAG, PREF) do {                             \
    if (PREF) { KSTAGE(KN, (kt_) + 1); VSTAGE(VN, (kt_) + 1); }                \
    float p0[8][4], p1[8][4];                                                  \
    _Pragma("unroll")                                                          \
    for (int nf = 0; nf < 8; ++nf) {                                           \
      bf16x8 k0_ = FRK(KC, nf * 16 + l15, l4);                                 \
      bf16x8 k1_ = FRK(KC, nf * 16 + l15, l4 + 4);                             \
      if (!(DIAG) || nf < 4) {                                                 \
        f32x4 z = {0.f, 0.f, 0.f, 0.f};                                        \
        z = __builtin_amdgcn_mfma_f32_16x16x32_bf16(k0_, qb00, z, 0, 0, 0);    \
        z = __builtin_amdgcn_mfma_f32_16x16x32_bf16(k1_, qb01, z, 0, 0, 0);    \
        _Pragma("unroll")                                                      \
        for (int r = 0; r < 4; ++r) {                                          \
          float sc = z[r];                                                     \
          if (DIAG && (nf * 16 + l4 * 4 + r) > (w * 16 + l15)) sc = -INFINITY; \
          p0[nf][r] = sc;                                                      \
        }                                                                      \
      } else {                                                                 \
        _Pragma("unroll")                                                      \
        for (int r = 0; r < 4; ++r) p0[nf][r] = -INFINITY;                     \
      }                                                                        \
      {                                                                        \
        f32x4 z = {0.f, 0.f, 0.f, 0.f};                                        \
        z = __builtin_amdgcn_mfma_f32_16x16x32_bf16(k0_, qb10, z, 0, 0, 0);    \
        z = __builtin_amdgcn_mfma_f32_16x16x32_bf16(k1_, qb11, z, 0, 0, 0);    \
        _Pragma("unroll")                                                      \
        for (int r = 0; r < 4; ++r) {                                          \
          float sc = z[r];                                                     \
          if (DIAG && (nf * 16 + l4 * 4 + r) > (64 + w * 16 + l15)) sc = -INFINITY; \
          p1[nf][r] = sc;                                                      \
        }                                                                      \
      }                                                                        \
    }                                                                          \
    SMAX8(p0, mrun0, lrun0, acc0);                                             \
    SMAX8(p1, mrun1, lrun1, acc1);                                             \
    PVHALF(p0, myP0, acc0, VC, 0);                                             \
    if (!(DIAG)) PVHALF(p0, myP0, acc0, VC, 1);                                \
    PVHALF(p1, myP1, acc1, VC, 0);                                             \
    PVHALF(p1, myP1, acc1, VC, 1);                                             \
    __syncthreads();                                                           \
  } while (0)

__global__ __launch_bounds__(256, 2) void k_flash(const ushort* __restrict__ qT,
                                                  const ushort* __restrict__ kT,
                                                  const ushort* __restrict__ vT,
                                                  ushort* __restrict__ AO) {
  __shared__ ushort Ks[2][128 * 64];
  __shared__ ushort Vs[2][64 * 128];
  __shared__ char Plds[4 * 4096];
  const int l = blockIdx.x;
  const int bh = (l & 7) * 4 + ((l >> 3) & 3);
  const int qt = (SEQ / 128 - 1) - (l >> 5);
  const int tid = threadIdx.x, w = tid >> 6, lane = tid & 63;
  const int l15 = lane & 15, l4 = lane >> 4;
  const size_t hb = (size_t)bh * SEQ * DK;
  const size_t vbase = (size_t)bh * DK * SEQ;
  const int qrow0 = qt * 128 + w * 16;
  const int qrow1 = qrow0 + 64;
  const bf16x8 qb00 = *(const bf16x8*)(qT + hb + (size_t)(qrow0 + l15) * 64 + l4 * 8);
  const bf16x8 qb01 = *(const bf16x8*)(qT + hb + (size_t)(qrow0 + l15) * 64 + 32 + l4 * 8);
  const bf16x8 qb10 = *(const bf16x8*)(qT + hb + (size_t)(qrow1 + l15) * 64 + l4 * 8);
  const bf16x8 qb11 = *(const bf16x8*)(qT + hb + (size_t)(qrow1 + l15) * 64 + 32 + l4 * 8);
  f32x4 acc0[4] = {}, acc1[4] = {};
  float mrun0 = -INFINITY, lrun0 = 0.f, mrun1 = -INFINITY, lrun1 = 0.f;
  char* myP0 = (char*)Plds + w * 4096;
  char* myP1 = myP0 + 2048;
  const int swz = (l15 & 7) << 4;
  ushort* kc = &Ks[0][0]; ushort* vc = &Vs[0][0];
  ushort* kn = &Ks[1][0]; ushort* vn = &Vs[1][0];
  KSTAGE(kc, 0); VSTAGE(vc, 0);
  __syncthreads();
  for (int kt = 0; kt < qt; ++kt) {
    STEP(kc, vc, kn, vn, kt, false, true);
    ushort* t;
    t = kc; kc = kn; kn = t;
    t = vc; vc = vn; vn = t;
  }
  STEP(kc, vc, kn, vn, qt, true, false);
  // deferred cross-lane l reduction (lanes l15+16*l4 share row l15)
  lrun0 += __shfl_xor(lrun0, 16); lrun0 += __shfl_xor(lrun0, 32);
  lrun1 += __shfl_xor(lrun1, 16); lrun1 += __shfl_xor(lrun1, 32);
  const int b = bh >> 4, h = bh & 15;
  float lq0[4], lq1[4];
#pragma unroll
  for (int r = 0; r < 4; ++r) {
    lq0[r] = __shfl(lrun0, l4 * 4 + r);
    lq1[r] = __shfl(lrun1, l4 * 4 + r);
  }
#pragma unroll
  for (int r = 0; r < 4; ++r) {
    float inv0 = 1.f / lq0[r], inv1 = 1.f / lq1[r];
    int qr0 = qrow0 + l4 * 4 + r, qr1 = qrow1 + l4 * 4 + r;
#pragma unroll
    for (int df = 0; df < 4; ++df) {
      AO[(size_t)(b * SEQ + qr0) * DM + h * 64 + df * 16 + l15] = f2bf(acc0[df][r] * inv0);
      AO[(size_t)(b * SEQ + qr1) * DM + h * 64 + df * 16 + l15] = f2bf(acc1[df][r] * inv1);
    }
  }
}

extern "C" void kernel_launch(void* const* d_in, const int* in_sizes, int n_in,
                              void* d_out, int out_size, void* d_ws, size_t ws_size,
                              hipStream_t stream) {
  const float* Q = (const float*)d_in[0];
  const float* K = (const float*)d_in[1];
  const float* V = (const float*)d_in[2];
  const float* wq = (const float*)d_in[3];
  const float* wk = (const float*)d_in[4];
  const float* wv = (const float*)d_in[5];
  const float* wo = (const float*)d_in[6];
  float* out = (float*)d_out;
  char* ws = (char*)d_ws;

  ushort* XQ = (ushort*)(ws + 0);          // 8 MB each, XQ/XK/XV contiguous
  ushort* XK = (ushort*)(ws + 8388608);
  ushort* WQ = (ushort*)(ws + 25165824);   // 2 MB each, WQ..WO contiguous
  ushort* qT = (ushort*)(ws + 33554432);   // 8 MB
  ushort* kT = (ushort*)(ws + 41943040);   // 8 MB
  ushort* YV = (ushort*)(ws + 50331648);   // 8 MB
  float* TAB = (float*)(ws + 58720256);    // 512 KB
  // stream-ordered reuse:
  ushort* vT = XQ;   // tr_v output (XQ consumed by gemm_qkv)
  ushort* AO = XK;   // flash output (XK consumed by gemm_qkv)

  const int NX4 = BATCH * SEQ * DM / 4;
  const int NW4 = DM * DM / 4;
  P4 xin = {Q, K, V, nullptr};
  P4 win = {wq, wk, wv, wo};
  k_castN<<<dim3(1024, 1, 3), 256, 0, stream>>>(xin, XQ, NX4);
  k_castN<<<dim3(1024, 1, 4), 256, 0, stream>>>(win, WQ, NW4);
  k_rope_tab<<<(SEQ * 32) / 256, 256, 0, stream>>>(TAB);

  const float QSCALE = 0.125f * 1.4426950408889634f;  // 1/sqrt(dk) * log2(e)
  k_gemm_qkv<<<768, 256, 0, stream>>>(XQ, WQ, qT, kT, YV, TAB, QSCALE,
                                      BATCH * SEQ, DM, DM);

  k_tr_v<<<dim3(SEQ / 64, BH), 256, 0, stream>>>(YV, vT);

  k_flash<<<BH * (SEQ / 128), 256, 0, stream>>>(qT, kT, vT, AO);

  k_gemm_f<<<512, 256, 0, stream>>>(AO, WQ + 3 * DM * DM, out, BATCH * SEQ, DM, DM);
}

// Round 10
// 120.011 us; speedup vs baseline: 1.9840x; 1.0586x over previous
//
#include <hip/hip_runtime.h>

#define SEQ 2048
#define BATCH 2
#define DM 1024
#define NH 16
#define DK 64
#define BH (BATCH*NH)

typedef __attribute__((ext_vector_type(8))) short bf16x8;
typedef __attribute__((ext_vector_type(4))) float f32x4;

__device__ __forceinline__ ushort f2bf(float f) {
  union { float f; unsigned u; } v; v.f = f;
  unsigned r = (v.u + 0x7fffu + ((v.u >> 16) & 1u)) >> 16;
  return (ushort)r;
}
__device__ __forceinline__ float bf2f(ushort h) {
  union { unsigned u; float f; } v; v.u = ((unsigned)h) << 16;
  return v.f;
}
__device__ __forceinline__ unsigned cvtpk(float lo, float hi) {
  unsigned r;
  asm("v_cvt_pk_bf16_f32 %0, %1, %2" : "=v"(r) : "v"(lo), "v"(hi));
  return r;
}

// counted-vmcnt sync primitives (T4)
#define WAITV4 asm volatile("s_waitcnt vmcnt(4)" ::: "memory")
#define WAITV3 asm volatile("s_waitcnt vmcnt(3)" ::: "memory")
#define WAITV2 asm volatile("s_waitcnt vmcnt(2)" ::: "memory")
#define WAITV0 asm volatile("s_waitcnt vmcnt(0)" ::: "memory")
#define WAITL0 asm volatile("s_waitcnt lgkmcnt(0)" ::: "memory")
#define BARR() __builtin_amdgcn_s_barrier()

// ---------------- batched cast fp32 -> bf16 (weights only now) ----------------
struct P4 { const float* p0; const float* p1; const float* p2; const float* p3; };
__global__ void k_castN(P4 in, ushort* __restrict__ out, int n4) {
  const float* src = (blockIdx.z == 0) ? in.p0 : (blockIdx.z == 1) ? in.p1
                    : (blockIdx.z == 2) ? in.p2 : in.p3;
  ushort* dst = out + (size_t)blockIdx.z * (size_t)n4 * 4;
  int i = blockIdx.x * blockDim.x + threadIdx.x;
  int st = gridDim.x * blockDim.x;
  for (; i < n4; i += st) {
    float4 v = reinterpret_cast<const float4*>(src)[i];
    ushort4 o;
    o.x = f2bf(v.x); o.y = f2bf(v.y); o.z = f2bf(v.z); o.w = f2bf(v.w);
    reinterpret_cast<ushort4*>(dst)[i] = o;
  }
}

// ---------------- RoPE cos/sin table: [SEQ][32] pairs ----------------
__global__ void k_rope_tab(float* __restrict__ tab) {
  int id = blockIdx.x * blockDim.x + threadIdx.x;
  if (id >= SEQ * 32) return;
  int s = id >> 5, i = id & 31;
  float inv = powf(10000.f, -(float)i / 32.f);
  float ang = (float)s * inv;
  float sn, cs;
  sincosf(ang, &sn, &cs);
  tab[id * 2] = cs;
  tab[id * 2 + 1] = sn;
}

// ---------------- async global->LDS 16B ----------------
__device__ __forceinline__ void gll16(const void* g, void* l) {
  __builtin_amdgcn_global_load_lds((const __attribute__((address_space(1))) void*)g,
                                   (__attribute__((address_space(3))) void*)l, 16, 0, 0);
}

// ---------------- QKV GEMM with FUSED fp32->bf16 A-cast + RoPE/V-transpose ----
// A read as fp32 (the raw Q/K/V inputs), reg-staged with cvt_pk -> ds_write.
// B (weights, pre-cast bf16) staged via global_load_lds, counted vmcnt.
// Pipeline invariant at each barrier: vm queue = [rloadA_next(4)] (+gllB later).
#define LOADA(R, kk_) do {                                                     \
    _Pragma("unroll")                                                          \
    for (int i_ = 0; i_ < 2; ++i_) {                                           \
      int row_ = i_ * 64 + (tid >> 2), c_ = (tid & 3) * 8;                     \
      const float4* s_ = (const float4*)(Afp + (size_t)(m0 + row_) * K + (kk_) + c_); \
      R[2 * i_] = s_[0]; R[2 * i_ + 1] = s_[1];                                \
    }                                                                          \
  } while (0)

#define AWRITE(AD, R) do {                                                     \
    _Pragma("unroll")                                                          \
    for (int i_ = 0; i_ < 2; ++i_) {                                           \
      int row_ = i_ * 64 + (tid >> 2), c_ = (tid & 3) * 8;                     \
      uint4 pk_;                                                               \
      pk_.x = cvtpk(R[2 * i_].x, R[2 * i_].y);                                 \
      pk_.y = cvtpk(R[2 * i_].z, R[2 * i_].w);                                 \
      pk_.z = cvtpk(R[2 * i_ + 1].x, R[2 * i_ + 1].y);                         \
      pk_.w = cvtpk(R[2 * i_ + 1].z, R[2 * i_ + 1].w);                         \
      *(uint4*)((AD) + row_ * 32 + c_) = pk_;                                  \
    }                                                                          \
  } while (0)

#define GLLB(BD, kk_) do {                                                     \
    gll16(Bw + (size_t)(n0 + w * 16 + lrow) * K + (kk_) + lcol, (void*)((BD) + w * 512));       \
    gll16(Bw + (size_t)(n0 + 64 + w * 16 + lrow) * K + (kk_) + lcol, (void*)((BD) + 2048 + w * 512)); \
  } while (0)

#define GCOMP(AS_, BS_) do {                                                   \
    bf16x8 af[4], bfr[4];                                                      \
    _Pragma("unroll")                                                          \
    for (int i = 0; i < 4; ++i)                                                \
      af[i] = *(const bf16x8*)((AS_) + (wr * 64 + i * 16 + l15) * 32 + l4 * 8);\
    _Pragma("unroll")                                                          \
    for (int i = 0; i < 4; ++i)                                                \
      bfr[i] = *(const bf16x8*)((BS_) + (wc * 64 + i * 16 + l15) * 32 + l4 * 8);\
    _Pragma("unroll")                                                          \
    for (int mi = 0; mi < 4; ++mi)                                             \
      _Pragma("unroll")                                                        \
      for (int ni = 0; ni < 4; ++ni)                                           \
        acc[mi][ni] = __builtin_amdgcn_mfma_f32_16x16x32_bf16(af[mi], bfr[ni], acc[mi][ni], 0, 0, 0); \
  } while (0)

// generic phase: compute CUR tile t; stage B(t+1) into NXT; write A(t+1) regs
// (RIN) into NXT; issue A-loads for t+2 into ROUT.
#define PHASE(CAS, CBS, NAS, NBS, RIN, ROUT, T2OK, t_) do {                    \
    GLLB(NBS, ((t_) + 1) * 32);                                                \
    WAITV2;                                                                    \
    AWRITE(NAS, RIN);                                                          \
    if (T2OK) LOADA(ROUT, ((t_) + 2) * 32);                                    \
    GCOMP(CAS, CBS);                                                           \
    if (T2OK) { WAITV4; } else { WAITV0; }                                     \
    WAITL0; BARR();                                                            \
  } while (0)

// grid: flat 768.  id%8 == m%8 -> XCD-local A panels + L2-resident B tiles.
__global__ __launch_bounds__(256) void k_gemm_qkv(const float* __restrict__ Qf,
                                                  const float* __restrict__ Kf,
                                                  const float* __restrict__ Vf,
                                                  const ushort* __restrict__ Bw0,
                                                  ushort* __restrict__ qT,
                                                  ushort* __restrict__ kT,
                                                  ushort* __restrict__ vT,
                                                  const float* __restrict__ tab,
                                                  float qscale, int M, int N, int K) {
  const int id = blockIdx.x;
  const int mlo = id & 7, nb = (id >> 3) & 7, mhi = (id >> 6) & 3, z = id >> 8;
  const int m0 = (mhi * 8 + mlo) * 128, n0 = nb * 128;
  const float* Afp = (z == 0) ? Qf : (z == 1) ? Kf : Vf;
  const ushort* Bw = Bw0 + (size_t)z * ((size_t)N * K);
  __shared__ ushort As0[128 * 32], Bs0[128 * 32];
  __shared__ ushort As1[128 * 32], Bs1[128 * 32];
  const int tid = threadIdx.x;
  const int w = tid >> 6, lane = tid & 63;
  const int l15 = lane & 15, l4 = lane >> 4;
  const int wr = w >> 1, wc = w & 1;
  const int lrow = lane >> 2, lcol = (lane & 3) * 8;
  float4 rA[4], rB[4];
  f32x4 acc[4][4] = {};
  // prologue: tile0 -> As0/Bs0 (drain once), tile1 A-loads in flight
  LOADA(rA, 0);
  GLLB(Bs0, 0);
  WAITV0;
  AWRITE(As0, rA);
  LOADA(rB, 32);
  WAITL0; BARR();
  // phases 0..29 (tiles 0..29), 2 per iter; NT=32 (K=1024)
  for (int t = 0; t < 30; t += 2) {
    PHASE(As0, Bs0, As1, Bs1, rB, rA, 1, t);
    PHASE(As1, Bs1, As0, Bs0, rA, rB, 1, t + 1);
  }
  // phase 30 (no t+2 load), phase 31 (compute only)
  PHASE(As0, Bs0, As1, Bs1, rB, rA, 0, 30);
  GCOMP(As1, Bs1);
  // epilogues
  if (z == 2) {
#pragma unroll
    for (int mi = 0; mi < 4; ++mi)
#pragma unroll
      for (int ni = 0; ni < 4; ++ni)
#pragma unroll
        for (int r = 0; r < 4; ++r) {
          int row = m0 + wr * 64 + mi * 16 + l4 * 4 + r;
          int col = n0 + wc * 64 + ni * 16 + l15;
          int bh2 = (row >> 11) * 16 + (col >> 6);
          int d = col & 63, s = row & (SEQ - 1);
          vT[((size_t)bh2 * 64 + d) * SEQ + s] = f2bf(acc[mi][ni][r]);
        }
  } else {
    const float scale = (z == 0) ? qscale : 1.0f;
    ushort* T = (z == 0) ? qT : kT;
    const bool odd = (l15 & 1);
#pragma unroll
    for (int mi = 0; mi < 4; ++mi)
#pragma unroll
      for (int ni = 0; ni < 4; ++ni)
#pragma unroll
        for (int r = 0; r < 4; ++r) {
          int row = m0 + wr * 64 + mi * 16 + l4 * 4 + r;
          int col = n0 + wc * 64 + ni * 16 + l15;
          float v = acc[mi][ni][r];
          float pv = __shfl_xor(v, 1);
          int s = row & (SEQ - 1);
          int d = col & 63;
          float2 cs = *(const float2*)(tab + ((size_t)s * 32 + (d >> 1)) * 2);
          float xe = odd ? pv : v, xo = odd ? v : pv;
          float outv = (odd ? (xe * cs.y + xo * cs.x) : (xe * cs.x - xo * cs.y)) * scale;
          int bh2 = (row >> 11) * 16 + (col >> 6);
          T[((size_t)bh2 * SEQ + s) * 64 + d] = f2bf(outv);
        }
  }
}

// ---------------- final GEMM: counted-vmcnt 2-deep pipeline, fp32 out --------
#define FSTAGE(AD, BD, kk_) do {                                               \
    gll16(A + (size_t)(m0 + srow) * K + (kk_) + scol, (void*)((AD) + w * 512));\
    gll16(Bw + (size_t)(n0 + srow) * K + (kk_) + scol, (void*)((BD) + w * 512));\
    gll16(Bw + (size_t)(n0 + 64 + srow) * K + (kk_) + scol, (void*)((BD) + 2048 + w * 512)); \
  } while (0)

#define FCOMP(AS_, BS_) do {                                                   \
    bf16x8 af[2], bfr[4];                                                      \
    _Pragma("unroll")                                                          \
    for (int i = 0; i < 2; ++i)                                                \
      af[i] = *(const bf16x8*)((AS_) + (wr * 32 + i * 16 + l15) * 32 + l4 * 8);\
    _Pragma("unroll")                                                          \
    for (int i = 0; i < 4; ++i)                                                \
      bfr[i] = *(const bf16x8*)((BS_) + (wc * 64 + i * 16 + l15) * 32 + l4 * 8);\
    _Pragma("unroll")                                                          \
    for (int mi = 0; mi < 2; ++mi)                                             \
      _Pragma("unroll")                                                        \
      for (int ni = 0; ni < 4; ++ni)                                           \
        acc[mi][ni] = __builtin_amdgcn_mfma_f32_16x16x32_bf16(af[mi], bfr[ni], acc[mi][ni], 0, 0, 0); \
  } while (0)

__global__ __launch_bounds__(256) void k_gemm_f(const ushort* __restrict__ A,
                                                const ushort* __restrict__ Bw,
                                                float* __restrict__ C, int M, int N, int K) {
  const int id = blockIdx.x;
  const int mlo = id & 7, nb = (id >> 3) & 7, mhi = id >> 6;
  const int m0 = (mhi * 8 + mlo) * 64, n0 = nb * 128;
  __shared__ ushort As0[64 * 32], Bs0[128 * 32];
  __shared__ ushort As1[64 * 32], Bs1[128 * 32];
  const int tid = threadIdx.x;
  const int w = tid >> 6, lane = tid & 63;
  const int l15 = lane & 15, l4 = lane >> 4;
  const int wr = w >> 1, wc = w & 1;
  const int srow = tid >> 2, scol = (tid & 3) * 8;
  f32x4 acc[2][4] = {};
  FSTAGE(As0, Bs0, 0);
  FSTAGE(As1, Bs1, 32);
  for (int kk = 0; kk < K - 64; kk += 64) {
    WAITV3; BARR();
    FCOMP(As0, Bs0);
    WAITL0; BARR();
    FSTAGE(As0, Bs0, kk + 64);
    WAITV3; BARR();
    FCOMP(As1, Bs1);
    WAITL0; BARR();
    if (kk + 96 < K) FSTAGE(As1, Bs1, kk + 96);
  }
  WAITV3; BARR();
  FCOMP(As0, Bs0);
  WAITV0; BARR();
  FCOMP(As1, Bs1);
#pragma unroll
  for (int mi = 0; mi < 2; ++mi)
#pragma unroll
    for (int ni = 0; ni < 4; ++ni)
#pragma unroll
      for (int r = 0; r < 4; ++r) {
        int row = m0 + wr * 32 + mi * 16 + l4 * 4 + r;
        int col = n0 + wc * 64 + ni * 16 + l15;
        C[(size_t)row * N + col] = acc[mi][ni][r];
      }
}

// ---------------- causal flash attention: QBLK=128, KVBLK=128 ----------------
#define KSTAGE(DST, kt_) do {                                                  \
    const ushort* kb_ = kT + hb + (size_t)(kt_) * 8192;                        \
    _Pragma("unroll")                                                          \
    for (int i_ = 0; i_ < 4; ++i_) {                                           \
      int tt_ = i_ * 256 + tid;                                                \
      int row_ = tt_ >> 3, c_ = (tt_ & 7) ^ (row_ & 7);                        \
      gll16(kb_ + (size_t)row_ * 64 + c_ * 8,                                  \
            (void*)((char*)(DST) + (i_ * 256 + w * 64) * 16));                 \
    }                                                                          \
  } while (0)

#define VSTAGE(DST, kt_) do {                                                  \
    const ushort* vb_ = vT + vbase + (size_t)(kt_) * 128;                      \
    _Pragma("unroll")                                                          \
    for (int i_ = 0; i_ < 4; ++i_) {                                           \
      int tt_ = i_ * 256 + tid;                                                \
      int row_ = tt_ >> 4, c_ = (tt_ & 15) ^ (row_ & 15);                      \
      gll16(vb_ + (size_t)row_ * SEQ + c_ * 8,                                 \
            (void*)((char*)(DST) + (i_ * 256 + w * 64) * 16));                 \
    }                                                                          \
  } while (0)

#define FRK(BASE, row_, cidx)                                                  \
  (*(const bf16x8*)((const char*)(BASE) + (row_) * 128 + ((((cidx) ^ ((row_) & 7)) & 7) * 16)))
#define FRV(BASE, row_, cidx)                                                  \
  (*(const bf16x8*)((const char*)(BASE) + (row_) * 256 + ((((cidx) ^ ((row_) & 15)) & 15) * 16)))

#define SMAX8(P, MRUN, LRUN, ACC) do {                                         \
    float mx = P[0][0];                                                        \
    _Pragma("unroll")                                                          \
    for (int nf = 0; nf < 8; ++nf)                                             \
      _Pragma("unroll")                                                        \
      for (int r = 0; r < 4; ++r) mx = fmaxf(mx, P[nf][r]);                    \
    mx = fmaxf(mx, __shfl_xor(mx, 16));                                        \
    mx = fmaxf(mx, __shfl_xor(mx, 32));                                        \
    if (!__all(mx <= MRUN)) {                                                  \
      const float mn = fmaxf(MRUN, mx);                                        \
      const float so = __builtin_amdgcn_exp2f(MRUN - mn);                      \
      float soq[4];                                                            \
      _Pragma("unroll")                                                        \
      for (int r = 0; r < 4; ++r) soq[r] = __shfl(so, l4 * 4 + r);             \
      _Pragma("unroll")                                                        \
      for (int df = 0; df < 4; ++df)                                           \
        _Pragma("unroll")                                                      \
        for (int r = 0; r < 4; ++r) ACC[df][r] *= soq[r];                      \
      LRUN *= so;                                                              \
      MRUN = mn;                                                               \
    }                                                                          \
    float rs = 0.f;                                                            \
    _Pragma("unroll")                                                          \
    for (int nf = 0; nf < 8; ++nf) {                                           \
      float e0 = __builtin_amdgcn_exp2f(P[nf][0] - MRUN);                      \
      float e1 = __builtin_amdgcn_exp2f(P[nf][1] - MRUN);                      \
      float e2 = __builtin_amdgcn_exp2f(P[nf][2] - MRUN);                      \
      float e3 = __builtin_amdgcn_exp2f(P[nf][3] - MRUN);                      \
      P[nf][0] = e0; P[nf][1] = e1; P[nf][2] = e2; P[nf][3] = e3;              \
      rs += (e0 + e1) + (e2 + e3);                                             \
    }                                                                          \
    LRUN += rs;                                                                \
  } while (0)

#define PVHALF(P, MYP, ACC, VC, H) do {                                        \
    _Pragma("unroll")                                                          \
    for (int i = 0; i < 4; ++i) {                                              \
      uint2 pk;                                                                \
      pk.x = cvtpk(P[(H) * 4 + i][0], P[(H) * 4 + i][1]);                      \
      pk.y = cvtpk(P[(H) * 4 + i][2], P[(H) * 4 + i][3]);                      \
      *(uint2*)((MYP) + ((l15 * 128 + i * 32 + l4 * 8) ^ swz)) = pk;           \
    }                                                                          \
    const bf16x8 pa0 = *(const bf16x8*)((MYP) + ((l15 * 128 + l4 * 16) ^ swz));\
    const bf16x8 pa1 = *(const bf16x8*)((MYP) + ((l15 * 128 + 64 + l4 * 16) ^ swz));\
    _Pragma("unroll")                                                          \
    for (int df = 0; df < 4; ++df) {                                           \
      bf16x8 v0_ = FRV(VC, df * 16 + l15, (H) * 8 + l4);                       \
      bf16x8 v1_ = FRV(VC, df * 16 + l15, (H) * 8 + l4 + 4);                   \
      ACC[df] = __builtin_amdgcn_mfma_f32_16x16x32_bf16(pa0, v0_, ACC[df], 0, 0, 0); \
      ACC[df] = __builtin_amdgcn_mfma_f32_16x16x32_bf16(pa1, v1_, ACC[df], 0, 0, 0); \
    }                                                                          \
  } while (0)

#define STEP(KC, VC, KN, VN, kt_, DIAG, PREF) do {                             \
    if (PREF) { KSTAGE(KN, (kt_) + 1); VSTAGE(VN, (kt_) + 1); }                \
    float p0[8][4], p1[8][4];                                                  \
    _Pragma("unroll")                                                          \
    for (int nf = 0; nf < 8; ++nf) {                                           \
      bf16x8 k0_ = FRK(KC, nf * 16 + l15, l4);                                 \
      bf16x8 k1_ = FRK(KC, nf * 16 + l15, l4 + 4);                             \
      if (!(DIAG) || nf < 4) {                                                 \
        f32x4 z = {0.f, 0.f, 0.f, 0.f};                                        \
        z = __builtin_amdgcn_mfma_f32_16x16x32_bf16(k0_, qb00, z, 0, 0, 0);    \
        z = __builtin_amdgcn_mfma_f32_16x16x32_bf16(k1_, qb01, z, 0, 0, 0);    \
        _Pragma("unroll")                                                      \
        for (int r = 0; r < 4; ++r) {                                          \
          float sc = z[r];                                                     \
          if (DIAG && (nf * 16 + l4 * 4 + r) > (w * 16 + l15)) sc = -INFINITY; \
          p0[nf][r] = sc;                                                      \
        }                                                                      \
      } else {                                                                 \
        _Pragma("unroll")                                                      \
        for (int r = 0; r < 4; ++r) p0[nf][r] = -INFINITY;                     \
      }                                                                        \
      {                                                                        \
        f32x4 z = {0.f, 0.f, 0.f, 0.f};                                        \
        z = __builtin_amdgcn_mfma_f32_16x16x32_bf16(k0_, qb10, z, 0, 0, 0);    \
        z = __builtin_amdgcn_mfma_f32_16x16x32_bf16(k1_, qb11, z, 0, 0, 0);    \
        _Pragma("unroll")                                                      \
        for (int r = 0; r < 4; ++r) {                                          \
          float sc = z[r];                                                     \
          if (DIAG && (nf * 16 + l4 * 4 + r) > (64 + w * 16 + l15)) sc = -INFINITY; \
          p1[nf][r] = sc;                                                      \
        }                                                                      \
      }                                                                        \
    }                                                                          \
    SMAX8(p0, mrun0, lrun0, acc0);                                             \
    SMAX8(p1, mrun1, lrun1, acc1);                                             \
    PVHALF(p0, myP0, acc0, VC, 0);                                             \
    if (!(DIAG)) PVHALF(p0, myP0, acc0, VC, 1);                                \
    PVHALF(p1, myP1, acc1, VC, 0);                                             \
    PVHALF(p1, myP1, acc1, VC, 1);                                             \
    __syncthreads();                                                           \
  } while (0)

__global__ __launch_bounds__(256, 2) void k_flash(const ushort* __restrict__ qT,
                                                  const ushort* __restrict__ kT,
                                                  const ushort* __restrict__ vT,
                                                  ushort* __restrict__ AO) {
  __shared__ ushort Ks[2][128 * 64];
  __shared__ ushort Vs[2][64 * 128];
  __shared__ char Plds[4 * 4096];
  const int l = blockIdx.x;
  const int bh = (l & 7) * 4 + ((l >> 3) & 3);
  const int qt = (SEQ / 128 - 1) - (l >> 5);
  const int tid = threadIdx.x, w = tid >> 6, lane = tid & 63;
  const int l15 = lane & 15, l4 = lane >> 4;
  const size_t hb = (size_t)bh * SEQ * DK;
  const size_t vbase = (size_t)bh * DK * SEQ;
  const int qrow0 = qt * 128 + w * 16;
  const int qrow1 = qrow0 + 64;
  const bf16x8 qb00 = *(const bf16x8*)(qT + hb + (size_t)(qrow0 + l15) * 64 + l4 * 8);
  const bf16x8 qb01 = *(const bf16x8*)(qT + hb + (size_t)(qrow0 + l15) * 64 + 32 + l4 * 8);
  const bf16x8 qb10 = *(const bf16x8*)(qT + hb + (size_t)(qrow1 + l15) * 64 + l4 * 8);
  const bf16x8 qb11 = *(const bf16x8*)(qT + hb + (size_t)(qrow1 + l15) * 64 + 32 + l4 * 8);
  f32x4 acc0[4] = {}, acc1[4] = {};
  float mrun0 = -INFINITY, lrun0 = 0.f, mrun1 = -INFINITY, lrun1 = 0.f;
  char* myP0 = (char*)Plds + w * 4096;
  char* myP1 = myP0 + 2048;
  const int swz = (l15 & 7) << 4;
  ushort* kc = &Ks[0][0]; ushort* vc = &Vs[0][0];
  ushort* kn = &Ks[1][0]; ushort* vn = &Vs[1][0];
  KSTAGE(kc, 0); VSTAGE(vc, 0);
  __syncthreads();
  for (int kt = 0; kt < qt; ++kt) {
    STEP(kc, vc, kn, vn, kt, false, true);
    ushort* t;
    t = kc; kc = kn; kn = t;
    t = vc; vc = vn; vn = t;
  }
  STEP(kc, vc, kn, vn, qt, true, false);
  lrun0 += __shfl_xor(lrun0, 16); lrun0 += __shfl_xor(lrun0, 32);
  lrun1 += __shfl_xor(lrun1, 16); lrun1 += __shfl_xor(lrun1, 32);
  const int b = bh >> 4, h = bh & 15;
  float lq0[4], lq1[4];
#pragma unroll
  for (int r = 0; r < 4; ++r) {
    lq0[r] = __shfl(lrun0, l4 * 4 + r);
    lq1[r] = __shfl(lrun1, l4 * 4 + r);
  }
#pragma unroll
  for (int r = 0; r < 4; ++r) {
    float inv0 = 1.f / lq0[r], inv1 = 1.f / lq1[r];
    int qr0 = qrow0 + l4 * 4 + r, qr1 = qrow1 + l4 * 4 + r;
#pragma unroll
    for (int df = 0; df < 4; ++df) {
      AO[(size_t)(b * SEQ + qr0) * DM + h * 64 + df * 16 + l15] = f2bf(acc0[df][r] * inv0);
      AO[(size_t)(b * SEQ + qr1) * DM + h * 64 + df * 16 + l15] = f2bf(acc1[df][r] * inv1);
    }
  }
}

extern "C" void kernel_launch(void* const* d_in, const int* in_sizes, int n_in,
                              void* d_out, int out_size, void* d_ws, size_t ws_size,
                              hipStream_t stream) {
  const float* Q = (const float*)d_in[0];
  const float* K = (const float*)d_in[1];
  const float* V = (const float*)d_in[2];
  const float* wq = (const float*)d_in[3];
  const float* wk = (const float*)d_in[4];
  const float* wv = (const float*)d_in[5];
  const float* wo = (const float*)d_in[6];
  float* out = (float*)d_out;
  char* ws = (char*)d_ws;

  ushort* qT = (ushort*)(ws + 0);          // 8 MB
  ushort* kT = (ushort*)(ws + 8388608);    // 8 MB
  ushort* vT = (ushort*)(ws + 16777216);   // 8 MB
  ushort* WQ = (ushort*)(ws + 25165824);   // 2 MB x4 (WQ,WK,WV,WO)
  ushort* AO = (ushort*)(ws + 33554432);   // 8 MB
  float* TAB = (float*)(ws + 41943040);    // 512 KB

  const int NW4 = DM * DM / 4;
  P4 win = {wq, wk, wv, wo};
  k_castN<<<dim3(1024, 1, 4), 256, 0, stream>>>(win, WQ, NW4);
  k_rope_tab<<<(SEQ * 32) / 256, 256, 0, stream>>>(TAB);

  const float QSCALE = 0.125f * 1.4426950408889634f;  // 1/sqrt(dk) * log2(e)
  // QKV projections: fused fp32 A-cast + RoPE/head-transpose/V-transpose
  k_gemm_qkv<<<768, 256, 0, stream>>>(Q, K, V, WQ, qT, kT, vT, TAB, QSCALE,
                                      BATCH * SEQ, DM, DM);

  k_flash<<<BH * (SEQ / 128), 256, 0, stream>>>(qT, kT, vT, AO);

  k_gemm_f<<<512, 256, 0, stream>>>(AO, WQ + 3 * DM * DM, out, BATCH * SEQ, DM, DM);
}